// Round 16
// baseline (871.698 us; speedup 1.0000x reference)
//
#include <hip/hip_runtime.h>

typedef float v2f __attribute__((ext_vector_type(2)));

// ---------------------------------------------------------------------------
// Workspace layout (float offsets). Total 45,248,512 floats = ~181 MB.
// ---------------------------------------------------------------------------
static constexpr size_t O_SMALL   = 0;
static constexpr size_t O_US3     = 3145728;
static constexpr size_t O_XF      = 7340032;
static constexpr size_t O_USFILT  = 11536384;
static constexpr size_t O_ENERGY  = 15730688;
static constexpr size_t O_MED     = 15764480;
static constexpr size_t O_NRM     = 15765504;
static constexpr size_t O_ATTNS   = 15767552;
static constexpr size_t O_CHPOOL  = 15783936;
static constexpr size_t O_CHW     = 15788032;
static constexpr size_t O_SPPOOL  = 15790080;
static constexpr size_t O_SPW     = 15855616;
static constexpr size_t O_QKV     = 15888384;
static constexpr size_t O_QKVDW   = 28471296;
static constexpr size_t O_OUTCONV = 41054208;
static constexpr size_t CA_USRED = 0, CA_IMGRED = 1, CA_Q1 = 2, CA_K1 = 3, CA_V1 = 4,
                        CA_Q2 = 5, CA_K2 = 6, CA_V2 = 7, CA_O1 = 8, CA_O2 = 9,
                        CA_T1 = 10, CA_T2 = 11;

// ===========================================================================
// Device bodies
// ===========================================================================

template<int Ci, int Co>
__device__ __forceinline__ void conv1d3_body(char* smem_raw, int bid,
    const float* __restrict__ in, const float* __restrict__ w,
    const float* __restrict__ bs, float* __restrict__ out)
{
    constexpr int T = 128;
    constexpr int G = 256 / Co;
    constexpr int N = T / G;
    auto lds = (float(*)[T + 2])smem_raw;
    int tid = threadIdx.x;
    int b  = bid >> 5;
    int t0 = (bid & 31) * T;
    const float* inb = in + (size_t)b * Ci * 4096;
    for (int i = tid; i < Ci * T; i += 256) {
        int ci = i / T, x = i % T;
        lds[ci][x + 1] = inb[ci * 4096 + t0 + x];
    }
    if (tid < Ci) {
        lds[tid][0]     = (t0 > 0)        ? inb[tid * 4096 + t0 - 1] : 0.f;
        lds[tid][T + 1] = (t0 + T < 4096) ? inb[tid * 4096 + t0 + T] : 0.f;
    }
    __syncthreads();
    int co = tid / G;
    int x0 = (tid % G) * N;
    float acc[N];
    float bias = bs[co];
#pragma unroll
    for (int j = 0; j < N; ++j) acc[j] = bias;
    const float* wb = w + co * Ci * 3;
    for (int ci = 0; ci < Ci; ++ci) {
        float w0 = wb[ci * 3], w1 = wb[ci * 3 + 1], w2 = wb[ci * 3 + 2];
        float a = lds[ci][x0], bb = lds[ci][x0 + 1];
#pragma unroll
        for (int j = 0; j < N; ++j) {
            float cc = lds[ci][x0 + 2 + j];
            acc[j] += w0 * a + w1 * bb + w2 * cc;
            a = bb; bb = cc;
        }
    }
    float* ob = out + ((size_t)b * Co + co) * 4096 + t0 + x0;
#pragma unroll
    for (int j = 0; j < N; ++j) ob[j] = fmaxf(acc[j], 0.f);
}

template<int Ci, int Co, int TY>
__device__ __forceinline__ void conv2d3_body(char* smem_raw, int bid,
    const float* __restrict__ in, const float* __restrict__ w,
    const float* __restrict__ bs, float* __restrict__ out)
{
    constexpr int G = 256 / (Co * TY);
    constexpr int N = 64 / G;
    auto lds = (float(*)[TY + 2][66])smem_raw;
    int tid = threadIdx.x;
    constexpr int NB = 64 / TY;
    int b  = bid / NB;
    int y0 = (bid % NB) * TY;
    const float* inb = in + (size_t)b * Ci * 4096;
    for (int i = tid; i < Ci * (TY + 2) * 64; i += 256) {
        int x  = i & 63;
        int ry = (i >> 6) % (TY + 2);
        int ci = i / ((TY + 2) * 64);
        int gy = y0 - 1 + ry;
        lds[ci][ry][x + 1] = (gy >= 0 && gy < 64) ? inb[ci * 4096 + gy * 64 + x] : 0.f;
    }
    for (int r = tid; r < Ci * (TY + 2); r += 256) {
        int ry = r % (TY + 2), ci = r / (TY + 2);
        lds[ci][ry][0] = 0.f; lds[ci][ry][65] = 0.f;
    }
    __syncthreads();
    int co   = tid / (TY * G);
    int ysub = (tid / G) % TY;
    int x0   = (tid % G) * N;
    float acc[N];
    float bias = bs[co];
#pragma unroll
    for (int j = 0; j < N; ++j) acc[j] = bias;
    const float* wb = w + co * Ci * 9;
    for (int ci = 0; ci < Ci; ++ci) {
        float wr[9];
#pragma unroll
        for (int k = 0; k < 9; ++k) wr[k] = wb[ci * 9 + k];
#pragma unroll
        for (int dy = 0; dy < 3; ++dy) {
            const float* lr = &lds[ci][ysub + dy][x0];
            float a = lr[0], bb = lr[1];
#pragma unroll
            for (int j = 0; j < N; ++j) {
                float cc = lr[2 + j];
                acc[j] += wr[dy * 3] * a + wr[dy * 3 + 1] * bb + wr[dy * 3 + 2] * cc;
                a = bb; bb = cc;
            }
        }
    }
    float* ob = out + ((size_t)b * Co + co) * 4096 + (y0 + ysub) * 64 + x0;
#pragma unroll
    for (int j = 0; j < N; ++j) ob[j] = fmaxf(acc[j], 0.f);
}

// 4096-pt radix-4 Stockham FFT, SINGLE 32KB LDS buffer.
__device__ __forceinline__ void fft4096_r4_sb(float2* A, int tid)
{
    int Ns = 1;
    for (int s = 0; s < 6; ++s) {
        float cfac = -0.25f / (float)Ns;
        float2 va[4][4];
#pragma unroll
        for (int r = 0; r < 4; ++r) {
            int j = (r << 8) + tid;
            va[r][0] = A[j];
            va[r][1] = A[j + 1024];
            va[r][2] = A[j + 2048];
            va[r][3] = A[j + 3072];
        }
        __syncthreads();
#pragma unroll
        for (int r = 0; r < 4; ++r) {
            int j = (r << 8) + tid;
            int jm = j & (Ns - 1);
            float rev = (float)jm * cfac;
            float s1 = __builtin_amdgcn_sinf(rev);
            float c1 = __builtin_amdgcn_cosf(rev);
            float c2 = c1 * c1 - s1 * s1, s2 = 2.f * c1 * s1;
            float c3 = c2 * c1 - s2 * s1, s3 = c2 * s1 + s2 * c1;
            float2 v0 = va[r][0], v1 = va[r][1], v2 = va[r][2], v3 = va[r][3];
            float2 u1 = make_float2(v1.x * c1 - v1.y * s1, v1.x * s1 + v1.y * c1);
            float2 u2 = make_float2(v2.x * c2 - v2.y * s2, v2.x * s2 + v2.y * c2);
            float2 u3 = make_float2(v3.x * c3 - v3.y * s3, v3.x * s3 + v3.y * c3);
            float t0x = v0.x + u2.x, t0y = v0.y + u2.y;
            float t1x = v0.x - u2.x, t1y = v0.y - u2.y;
            float t2x = u1.x + u3.x, t2y = u1.y + u3.y;
            float t3x = u1.x - u3.x, t3y = u1.y - u3.y;
            int base = ((j - jm) << 2) + jm;
            A[base]          = make_float2(t0x + t2x, t0y + t2y);
            A[base + Ns]     = make_float2(t1x + t3y, t1y - t3x);
            A[base + 2 * Ns] = make_float2(t0x - t2x, t0y - t2y);
            A[base + 3 * Ns] = make_float2(t1x - t3y, t1y + t3x);
        }
        __syncthreads();
        Ns <<= 2;
    }
}

__device__ __forceinline__ void fft_fwd_body(char* smem_raw, int row,
    const float* __restrict__ us3, float* __restrict__ xf)
{
    float2* A = (float2*)smem_raw;
    int tid = threadIdx.x;
    const float* x = us3 + (size_t)row * 4096;
    for (int r = 0; r < 16; ++r) {
        int i = (r << 8) + tid;
        A[i] = make_float2(x[i], 0.f);
    }
    __syncthreads();
    fft4096_r4_sb(A, tid);
    float* out = xf + (size_t)row * 4098;
    for (int r = 0; r < 9; ++r) {
        int f = (r << 8) + tid;
        if (f < 2049) {
            out[2 * f]     = A[f].x * (1.f / 64.f);
            out[2 * f + 1] = A[f].y * (1.f / 64.f);
        }
    }
}

__device__ __forceinline__ void energy_body(int bid,
    const float* __restrict__ xf, float* __restrict__ energy)
{
    int idx = bid * 256 + threadIdx.x;
    if (idx >= 16 * 2049) return;
    int b = idx / 2049, f = idx % 2049;
    const float* p = xf + (size_t)b * 64 * 4098 + 2 * f;
    float e = 0.f;
    for (int ch = 0; ch < 64; ++ch) {
        float re = p[0], im = p[1];
        e += re * re + im * im;
        p += 4098;
    }
    energy[idx] = e;
}

__device__ __forceinline__ void median_body(char* smem_raw, int b,
    const float* __restrict__ energy, float* __restrict__ med)
{
    float* s = (float*)smem_raw;
    int tid = threadIdx.x;
    for (int r = 0; r < 16; ++r) {
        int i = (r << 8) + tid;
        s[i] = (i < 2049) ? energy[b * 2049 + i] : 3.0e38f;
    }
    __syncthreads();
    for (int k = 2; k <= 4096; k <<= 1) {
        for (int j = k >> 1; j > 0; j >>= 1) {
            for (int r = 0; r < 16; ++r) {
                int i = (r << 8) + tid;
                int ixj = i ^ j;
                if (ixj > i) {
                    bool up = ((i & k) == 0);
                    float a = s[i], bb = s[ixj];
                    if ((a > bb) == up) { s[i] = bb; s[ixj] = a; }
                }
            }
            __syncthreads();
        }
    }
    if (tid == 0) med[b] = s[1024];
}

// filter + irfft + FUSED 4:1 adaptive pooling -> us_redT (us_filt never
// materialized: its only consumer was the pooling).
__device__ __forceinline__ void filter_ifft_body(char* smem_raw, int row,
    const float* __restrict__ xf, const float* __restrict__ energy,
    const float* __restrict__ med, const float* __restrict__ aff_w,
    const float* __restrict__ aff_wh, const float* __restrict__ thr_p,
    float* __restrict__ us_redT)
{
    float2* A = (float2*)smem_raw;
    int b = row >> 6, ch = row & 63;
    int tid = threadIdx.x;
    float thr = thr_p[0];
    float mden = med[b] + 1e-6f;
    float w0r = aff_w[2 * ch], w0i = aff_w[2 * ch + 1];
    float whr = aff_wh[2 * ch], whi = aff_wh[2 * ch + 1];
    const float* X = xf + (size_t)row * 4098;
    const float* E = energy + b * 2049;
    for (int r = 0; r < 9; ++r) {
        int f = (r << 8) + tid;
        if (f < 2049) {
            float re = X[2 * f], im = X[2 * f + 1];
            float mask = (E[f] / mden > thr) ? 1.f : 0.f;
            float wr = w0r + mask * whr;
            float wi = w0i + mask * whi;
            float xr = re * wr - im * wi;
            float xi = re * wi + im * wr;
            A[f] = make_float2(xr, -xi);
            if (f >= 1 && f <= 2047) A[4096 - f] = make_float2(xr, xi);
        }
    }
    __syncthreads();
    fft4096_r4_sb(A, tid);
    // pooled row (1024) = mean of 4 adjacent irfft samples, with ortho 1/64:
    float* outp = us_redT + (size_t)row * 1024;
    const float SCL = 0.25f * (1.f / 64.f);
#pragma unroll
    for (int r = 0; r < 4; ++r) {
        int s4 = (r << 8) + tid;
        float v = (A[4 * s4].x + A[4 * s4 + 1].x + A[4 * s4 + 2].x + A[4 * s4 + 3].x) * SCL;
        outp[s4] = v;
    }
}

// 1x1 conv 64->192, register-blocked, packed-fp32
__device__ __forceinline__ void qkv1x1_body(int bid, const float* __restrict__ y,
    const float* __restrict__ w, const float* __restrict__ bs, float* __restrict__ out)
{
    int oc = bid & 3;
    int pc = (bid >> 2) & 15;
    int b  = bid >> 6;
    int p = pc * 256 + threadIdx.x;
    const float* inb = y + (size_t)b * 262144 + p;
    v2f reg[32];
#pragma unroll
    for (int ci = 0; ci < 32; ++ci) {
        v2f r; r.x = inb[(2 * ci) * 4096]; r.y = inb[(2 * ci + 1) * 4096];
        reg[ci] = r;
    }
    float* ob = out + (size_t)b * 786432 + (size_t)oc * 48 * 4096 + p;
    for (int o = 0; o < 48; ++o) {
        const v2f* wr = (const v2f*)(w + (oc * 48 + o) * 64);
        v2f s2 = {0.f, 0.f};
#pragma unroll
        for (int ci = 0; ci < 32; ++ci) s2 = wr[ci] * reg[ci] + s2;
        ob[o * 4096] = bs[oc * 48 + o] + s2.x + s2.y;
    }
}

// depthwise 3x3 pad=1, 192 channels
__device__ __forceinline__ void dwconv_body(int bid, const float* __restrict__ in,
    const float* __restrict__ w, const float* __restrict__ bs, float* __restrict__ out)
{
    int idx = bid * 256 + threadIdx.x;
    int x = idx & 63, yy = (idx >> 6) & 63;
    int c = (idx >> 12) % 192;
    const float* p = in + idx;
    const float* wp = w + c * 9;
    float acc = bs[c];
    bool ym = yy > 0, yp = yy < 63, xm = x > 0, xp = x < 63;
    float s = wp[4] * p[0];
    if (ym) { s += wp[1] * p[-64]; if (xm) s += wp[0] * p[-65]; if (xp) s += wp[2] * p[-63]; }
    if (xm) s += wp[3] * p[-1];
    if (xp) s += wp[5] * p[1];
    if (yp) { s += wp[7] * p[64];  if (xm) s += wp[6] * p[63];  if (xp) s += wp[8] * p[65]; }
    out[idx] = acc + s;
}

// fc over the "faithful reshape"
__device__ __forceinline__ void fc_body(int bid, const float* __restrict__ qkv_dw,
    const float* __restrict__ fw, const float* __restrict__ fb, float* __restrict__ fcv)
{
    int idx = bid * 256 + threadIdx.x;
    int k = idx & 15;
    int p = (idx >> 4) & 4095;
    int b = idx >> 16;
    const float* base = qkv_dw + (size_t)b * 786432;
    float u[12];
#pragma unroll
    for (int i = 0; i < 12; ++i) u[i] = base[p * 192 + i * 16 + k];
#pragma unroll
    for (int o = 0; o < 9; ++o) {
        float s = fb[o];
#pragma unroll
        for (int i = 0; i < 12; ++i) s += fw[o * 12 + i] * u[i];
        fcv[(((size_t)b * 16 + k) * 9 + o) * 4096 + p] = s;
    }
}

// grouped conv 144->64 g=16, LDS-tiled (needs 23760 B)
__device__ __forceinline__ void depconv2_body(char* smem_raw, int bid,
    const float* __restrict__ fcv, const float* __restrict__ w,
    const float* __restrict__ bs, float* __restrict__ out)
{
    auto lds = (float(*)[10][66])smem_raw;
    int band = bid & 7;
    int g    = (bid >> 3) & 15;
    int b    = bid >> 7;
    int y0 = band * 8;
    int tid = threadIdx.x;
    const float* inb = fcv + ((size_t)(b * 16 + g) * 9) * 4096;
    for (int i = tid; i < 9 * 10 * 64; i += 256) {
        int x  = i & 63;
        int ry = (i >> 6) % 10;
        int ci = i / 640;
        int gy = y0 - 1 + ry;
        lds[ci][ry][x + 1] = (gy >= 0 && gy < 64) ? inb[ci * 4096 + gy * 64 + x] : 0.f;
    }
    for (int i = tid; i < 90; i += 256) {
        int ry = i % 10, ci = i / 10;
        lds[ci][ry][0] = 0.f; lds[ci][ry][65] = 0.f;
    }
    __syncthreads();
    int co   = tid >> 6;
    int ysub = (tid >> 3) & 7;
    int x0   = (tid & 7) * 8;
    int ocg  = g * 4 + co;
    float acc[8];
    float bias = bs[ocg];
#pragma unroll
    for (int j = 0; j < 8; ++j) acc[j] = bias;
    const float* wb = w + ocg * 81;
    for (int ci = 0; ci < 9; ++ci) {
        float wr[9];
#pragma unroll
        for (int k = 0; k < 9; ++k) wr[k] = wb[ci * 9 + k];
#pragma unroll
        for (int dy = 0; dy < 3; ++dy) {
            const float* lr = &lds[ci][ysub + dy][x0];
            float a = lr[0], bb = lr[1];
#pragma unroll
            for (int j = 0; j < 8; ++j) {
                float cc = lr[2 + j];
                acc[j] += wr[dy * 3] * a + wr[dy * 3 + 1] * bb + wr[dy * 3 + 2] * cc;
                a = bb; bb = cc;
            }
        }
    }
    float* ob = out + ((size_t)b * 64 + ocg) * 4096 + (y0 + ysub) * 64 + x0;
#pragma unroll
    for (int j = 0; j < 8; ++j) ob[j] = acc[j];
}

// L2 norms of q/k rows
__device__ __forceinline__ void qknorm_body(char* smem_raw, int row,
    const float* __restrict__ qkv_dw, float* __restrict__ nrm)
{
    float* red = (float*)smem_raw;
    int which = row >> 10;
    int r = row & 1023;
    int b = r >> 6, hd = r & 63;
    const float* p = qkv_dw + ((size_t)b * 192 + which * 64 + hd) * 4096;
    float s = 0.f;
    for (int i = threadIdx.x; i < 4096; i += 256) { float v = p[i]; s += v * v; }
    red[threadIdx.x] = s;
    __syncthreads();
    for (int st = 128; st > 0; st >>= 1) {
        if (threadIdx.x < st) red[threadIdx.x] += red[threadIdx.x + st];
        __syncthreads();
    }
    if (threadIdx.x == 0) nrm[row] = sqrtf(red[0]);
}

// channel attention partials (arena-based LDS: 16640 B)
__device__ __forceinline__ void chan_attn_part_body(char* smem_raw, int blk,
    const float* __restrict__ qkv_dw, float* __restrict__ part)
{
    auto Qs  = (float(*)[130])smem_raw;
    auto Ks2 = (float(*)[130])(smem_raw + 16 * 130 * 4);
    int nc = blk & 7;
    int bh = blk >> 3;
    int b = bh >> 2, h = bh & 3;
    int c = threadIdx.x >> 4, d = threadIdx.x & 15;
    const float* qbase = qkv_dw + ((size_t)b * 192 + h * 16) * 4096 + nc * 512;
    const float* kbase = qkv_dw + ((size_t)b * 192 + 64 + h * 16) * 4096 + nc * 512;
    float s = 0.f;
    for (int n0 = 0; n0 < 512; n0 += 128) {
        __syncthreads();
        for (int r = 0; r < 8; ++r) {
            int i = (r << 8) + threadIdx.x;
            int row = i >> 7, col = i & 127;
            Qs[row][col]  = qbase[(size_t)row * 4096 + n0 + col];
            Ks2[row][col] = kbase[(size_t)row * 4096 + n0 + col];
        }
        __syncthreads();
#pragma unroll 8
        for (int n = 0; n < 128; ++n) s += Qs[c][n] * Ks2[d][n];
    }
    part[(size_t)blk * 256 + threadIdx.x] = s;
}

// channel pooling (wave-per-row shuffle reduction)
__device__ __forceinline__ void chpool2_body(int bid, const float* __restrict__ t1,
    const float* __restrict__ t2, float* __restrict__ chpool)
{
    int rg = bid & 15;
    int b  = bid >> 4;
    int wave = threadIdx.x >> 6, lane = threadIdx.x & 63;
    int c = rg * 4 + wave;
    const float* p1 = t1 + ((size_t)b * 64 + c) * 1024;
    const float* p2 = t2 + ((size_t)b * 64 + c) * 1024;
    float m1 = 0.f, x1 = -3e38f, m2 = 0.f, x2 = -3e38f;
#pragma unroll
    for (int i = 0; i < 16; ++i) {
        int p = lane + i * 64;
        float a = p1[p], bb = p2[p];
        m1 += a; x1 = fmaxf(x1, a);
        m2 += bb; x2 = fmaxf(x2, bb);
    }
    for (int off = 32; off > 0; off >>= 1) {
        m1 += __shfl_xor(m1, off);
        x1 = fmaxf(x1, __shfl_xor(x1, off));
        m2 += __shfl_xor(m2, off);
        x2 = fmaxf(x2, __shfl_xor(x2, off));
    }
    if (lane == 0) {
        chpool[b * 256 + c]       = m1 * (1.f / 1024.f);
        chpool[b * 256 + 64 + c]  = x1;
        chpool[b * 256 + 128 + c] = m2 * (1.f / 1024.f);
        chpool[b * 256 + 192 + c] = x2;
    }
}

// spatial pooling over channels
__device__ __forceinline__ void sppool_body(int bid, const float* __restrict__ t1,
    const float* __restrict__ t2, float* __restrict__ sppool)
{
    int b = bid >> 2;
    int p = (bid & 3) * 256 + threadIdx.x;
    float m1 = 0.f, x1 = -3e38f, m2 = 0.f, x2 = -3e38f;
    const float* p1 = t1 + (size_t)b * 65536 + p;
    const float* p2 = t2 + (size_t)b * 65536 + p;
    for (int c = 0; c < 64; ++c) {
        float a = p1[c * 1024], bb = p2[c * 1024];
        m1 += a; x1 = fmaxf(x1, a);
        m2 += bb; x2 = fmaxf(x2, bb);
    }
    sppool[b * 4096 + p]        = m1 * (1.f / 64.f);
    sppool[b * 4096 + 1024 + p] = x1;
    sppool[b * 4096 + 2048 + p] = m2 * (1.f / 64.f);
    sppool[b * 4096 + 3072 + p] = x2;
}

// channel gates (first 64 threads active)
__device__ __forceinline__ void chgate_body(int b, const float* __restrict__ chpool,
    const float* __restrict__ w1, const float* __restrict__ b1,
    const float* __restrict__ w2, const float* __restrict__ b2, float* __restrict__ chw)
{
    int c = threadIdx.x;
    if (c >= 64) return;
    float a1 = b1[0], a2 = b2[0];
    for (int ic = 0; ic < 4; ++ic) {
        const float* cp = chpool + b * 256 + ic * 64;
        for (int d = -1; d <= 1; ++d) {
            int cc = c + d;
            if (cc >= 0 && cc < 64) {
                a1 += w1[ic * 3 + d + 1] * cp[cc];
                a2 += w2[ic * 3 + d + 1] * cp[cc];
            }
        }
    }
    float mx = fmaxf(a1, a2);
    float e1 = __expf(a1 - mx), e2 = __expf(a2 - mx);
    float inv = 1.f / (e1 + e2);
    chw[b * 64 + c]        = e1 * inv;
    chw[1024 + b * 64 + c] = e2 * inv;
}

// spatial gates
__device__ __forceinline__ void spgate_body(int bid, const float* __restrict__ sppool,
    const float* __restrict__ w1, const float* __restrict__ b1,
    const float* __restrict__ w2, const float* __restrict__ b2, float* __restrict__ spw)
{
    int idx = bid * 256 + threadIdx.x;
    int p = idx & 1023;
    int b = idx >> 10;
    int y = p >> 5, x = p & 31;
    float a1 = b1[0], a2 = b2[0];
    for (int ic = 0; ic < 4; ++ic) {
        const float* sp = sppool + b * 4096 + ic * 1024;
        for (int dy = -3; dy <= 3; ++dy) {
            int yy = y + dy;
            if (yy < 0 || yy > 31) continue;
            for (int dx = -3; dx <= 3; ++dx) {
                int xx = x + dx;
                if (xx < 0 || xx > 31) continue;
                float v = sp[yy * 32 + xx];
                int wi = ic * 49 + (dy + 3) * 7 + (dx + 3);
                a1 += w1[wi] * v;
                a2 += w2[wi] * v;
            }
        }
    }
    float mx = fmaxf(a1, a2);
    float e1 = __expf(a1 - mx), e2 = __expf(a2 - mx);
    float inv = 1.f / (e1 + e2);
    spw[idx]         = e1 * inv;
    spw[16384 + idx] = e2 * inv;
}

// ===========================================================================
// Fused dispatcher kernels
// ===========================================================================

__global__ __launch_bounds__(256) void s1_kernel(const float* us_in, const float* uw, const float* ub,
    float* uo, const float* iin, const float* iw, const float* ib, float* io)
{
    __shared__ __align__(16) char smem[3168];
    if (blockIdx.x < 512) conv1d3_body<1, 16>(smem, blockIdx.x, us_in, uw, ub, uo);
    else                  conv2d3_body<3, 16, 2>(smem, blockIdx.x - 512, iin, iw, ib, io);
}

__global__ __launch_bounds__(256) void s2_kernel(const float* ui, const float* uw, const float* ub,
    float* uo, const float* ii, const float* iw, const float* ib, float* io)
{
    __shared__ __align__(16) char smem[16896];
    if (blockIdx.x < 512) conv1d3_body<16, 32>(smem, blockIdx.x, ui, uw, ub, uo);
    else                  conv2d3_body<16, 32, 2>(smem, blockIdx.x - 512, ii, iw, ib, io);
}

__global__ __launch_bounds__(256) void s3_kernel(const float* ui, const float* uw, const float* ub,
    float* uo, const float* ii, const float* iw, const float* ib, float* io)
{
    __shared__ __align__(16) char smem[33792];
    if (blockIdx.x < 512) conv1d3_body<32, 64>(smem, blockIdx.x, ui, uw, ub, uo);
    else                  conv2d3_body<32, 64, 2>(smem, blockIdx.x - 512, ii, iw, ib, io);
}

__global__ __launch_bounds__(256) void s4_kernel(const float* us3, float* xf,
    const float* y, const float* qw, const float* qb, float* qkv)
{
    __shared__ __align__(16) char smem[32768];
    if (blockIdx.x < 1024) fft_fwd_body(smem, blockIdx.x, us3, xf);
    else                   qkv1x1_body(blockIdx.x - 1024, y, qw, qb, qkv);
}

__global__ __launch_bounds__(256) void s5_kernel(const float* qkv, const float* dww,
    const float* dwb, float* qkv_dw, const float* xf, float* energy)
{
    if (blockIdx.x < 49152) dwconv_body(blockIdx.x, qkv, dww, dwb, qkv_dw);
    else                    energy_body(blockIdx.x - 49152, xf, energy);
}

// s6: fc || median || chan_attn partials (arena 16640 B)
__global__ __launch_bounds__(256) void s6_kernel(const float* qkv_dw, const float* fw,
    const float* fb, float* fcv, const float* energy, float* med, float* part)
{
    __shared__ __align__(16) char smem[16640];
    if (blockIdx.x < 4096)      fc_body(blockIdx.x, qkv_dw, fw, fb, fcv);
    else if (blockIdx.x < 4112) median_body(smem, blockIdx.x - 4096, energy, med);
    else                        chan_attn_part_body(smem, blockIdx.x - 4112, qkv_dw, part);
}

// s7: depconv || qknorm || filter+irfft+pool (arena 32 KB)
__global__ __launch_bounds__(256) void s7_kernel(const float* fcv, const float* dw,
    const float* db, float* out_conv, const float* qkv_dw, float* nrm,
    const float* xf, const float* energy, const float* med, const float* aw,
    const float* awh, const float* thr, float* us_redT)
{
    __shared__ __align__(16) char smem[32768];
    if (blockIdx.x < 2048)      depconv2_body(smem, blockIdx.x, fcv, dw, db, out_conv);
    else if (blockIdx.x < 4096) qknorm_body(smem, blockIdx.x - 2048, qkv_dw, nrm);
    else                        filter_ifft_body(smem, blockIdx.x - 4096, xf, energy, med, aw, awh, thr, us_redT);
}

// zero o1t/o2t numerators + ls + kmax accumulators
__global__ __launch_bounds__(256) void zero_kernel(float* o1t, float* o2t, float* lsg,
                                                   unsigned* kmax2)
{
    int idx = blockIdx.x * 256 + threadIdx.x;
    if (idx < 1048576) { o1t[idx] = 0.f; o2t[idx] = 0.f; }
    if (idx < 131072) lsg[idx] = 0.f;
    if (idx < 128) kmax2[idx] = 0u;
}

__global__ __launch_bounds__(256) void s16_kernel(const float* t1, const float* t2,
    float* chpool, float* sppool)
{
    if (blockIdx.x < 256) chpool2_body(blockIdx.x, t1, t2, chpool);
    else                  sppool_body(blockIdx.x - 256, t1, t2, sppool);
}

__global__ __launch_bounds__(256) void s17_kernel(const float* sppool, const float* sw1,
    const float* sb1, const float* sw2, const float* sb2, float* spw,
    const float* chpool, const float* cw1, const float* cb1, const float* cw2,
    const float* cb2, float* chw)
{
    if (blockIdx.x < 64) spgate_body(blockIdx.x, sppool, sw1, sb1, sw2, sb2, spw);
    else                 chgate_body(blockIdx.x - 64, chpool, cw1, cb1, cw2, cb2, chw);
}

// chan_attn merge + softmax (64 blocks)
__global__ __launch_bounds__(256) void chan_attn_merge_kernel(
    const float* __restrict__ part, const float* __restrict__ nrm,
    const float* __restrict__ temp, float* __restrict__ attn_s)
{
    int bh = blockIdx.x;
    int b = bh >> 2, h = bh & 3;
    int c = threadIdx.x >> 4, d = threadIdx.x & 15;
    float s = 0.f;
#pragma unroll
    for (int i = 0; i < 8; ++i) s += part[(size_t)(bh * 8 + i) * 256 + threadIdx.x];
    float nq = fmaxf(nrm[b * 64 + h * 16 + c], 1e-12f);
    float nk = fmaxf(nrm[1024 + b * 64 + h * 16 + d], 1e-12f);
    s = s / (nq * nk) * temp[h];
    __shared__ float S[16][17];
    S[c][d] = s;
    __syncthreads();
    if (threadIdx.x < 16) {
        int cc = threadIdx.x;
        float mx = -3e30f;
        for (int dd = 0; dd < 16; ++dd) mx = fmaxf(mx, S[cc][dd]);
        float sm = 0.f;
        float e[16];
        for (int dd = 0; dd < 16; ++dd) { e[dd] = __expf(S[cc][dd] - mx); sm += e[dd]; }
        float inv = 1.f / sm;
        float* dst = attn_s + (size_t)bh * 256 + cc * 16;
        for (int dd = 0; dd < 16; ++dd) dst[dd] = e[dd] * inv;
    }
}

// ===========================================================================
// Standalone kernels
// ===========================================================================

// attn@v + 1x1 proj + out_conv add, with FUSED 4:1 pooling -> img_redT
// (img_feat never materialized: its only consumer was the pooling).
__global__ __launch_bounds__(256, 2) void attnproj_kernel(const float* __restrict__ attn_s,
    const float* __restrict__ qkv_dw, const float* __restrict__ outconv,
    const float* __restrict__ pw, const float* __restrict__ pb, float* __restrict__ img_redT)
{
    int blk = blockIdx.x;
    int oc = blk & 1;
    int pc = (blk >> 1) & 15;
    int b  = blk >> 5;
    int tid = threadIdx.x;
    int n = pc * 256 + tid;
    const float* vb = qkv_dw + ((size_t)b * 192 + 128) * 4096 + n;
    v2f v[32];
#pragma unroll
    for (int i = 0; i < 32; ++i) {
        v2f r; r.x = vb[(2 * i) * 4096]; r.y = vb[(2 * i + 1) * 4096];
        v[i] = r;
    }
    const float* ab = attn_s + (size_t)b * 1024;
    for (int h = 0; h < 4; ++h) {
        v2f tmp[8];
#pragma unroll
        for (int c2 = 0; c2 < 8; ++c2) {
            v2f s2a = {0.f, 0.f}, s2b = {0.f, 0.f};
            const v2f* r0 = (const v2f*)(ab + (h * 16 + 2 * c2) * 16);
            const v2f* r1 = (const v2f*)(ab + (h * 16 + 2 * c2 + 1) * 16);
#pragma unroll
            for (int d2 = 0; d2 < 8; ++d2) {
                s2a = r0[d2] * v[h * 8 + d2] + s2a;
                s2b = r1[d2] * v[h * 8 + d2] + s2b;
            }
            v2f t; t.x = s2a.x + s2a.y; t.y = s2b.x + s2b.y;
            tmp[c2] = t;
        }
#pragma unroll
        for (int c2 = 0; c2 < 8; ++c2) v[h * 8 + c2] = tmp[c2];
    }
    const float* ocb = outconv + (size_t)b * 262144 + (size_t)oc * 32 * 4096 + n;
    float* orow = img_redT + ((size_t)b * 64 + (size_t)oc * 32) * 1024 + (n >> 2);
    for (int o = 0; o < 32; ++o) {
        const v2f* wr = (const v2f*)(pw + (oc * 32 + o) * 64);
        v2f s2 = {0.f, 0.f};
#pragma unroll
        for (int c2 = 0; c2 < 32; ++c2) s2 = wr[c2] * v[c2] + s2;
        float val = pb[oc * 32 + o] + ocb[o * 4096] + s2.x + s2.y;
        // 4:1 pool across 4 consecutive lanes (consecutive n within a wave)
        float s = val + __shfl_xor(val, 1);
        s += __shfl_xor(s, 2);
        if ((tid & 3) == 0) orow[(size_t)o * 1024] = s * 0.25f;
    }
}

// shared qkv projection with FUSED kmax (wave-reduced atomicMax of k-norm^2)
__global__ __launch_bounds__(256, 2) void caqkv2_kernel(const float* __restrict__ us_redT,
    const float* __restrict__ img_redT, const float* __restrict__ qw, const float* __restrict__ qb,
    float* __restrict__ q1, float* __restrict__ k1, float* __restrict__ v1,
    float* __restrict__ q2, float* __restrict__ k2, float* __restrict__ v2,
    unsigned* __restrict__ kmax2)
{
    int blk = blockIdx.x;
    int h  = blk & 3;
    int pc = (blk >> 2) & 3;
    int b  = (blk >> 4) & 15;
    int m  = blk >> 8;
    int l = pc * 256 + threadIdx.x;
    const float* in = (m ? img_redT : us_redT) + (size_t)b * 65536 + l;
    v2f reg[32];
#pragma unroll
    for (int i = 0; i < 32; ++i) {
        v2f r; r.x = in[(2 * i) * 1024]; r.y = in[(2 * i + 1) * 1024];
        reg[i] = r;
    }
    size_t rowoff = ((size_t)(b * 4 + h) * 1024 + l) * 16;
    float* dst[3] = { (m ? q2 : q1) + rowoff, (m ? k2 : k1) + rowoff, (m ? v2 : v1) + rowoff };
    float knorm2 = 0.f;
#pragma unroll
    for (int which = 0; which < 3; ++which) {
        float* dp = dst[which];
        for (int d = 0; d < 16; ++d) {
            int o = h * 48 + which * 16 + d;
            const v2f* wr = (const v2f*)(qw + o * 64);
            v2f s2 = {0.f, 0.f};
#pragma unroll
            for (int i = 0; i < 32; ++i) s2 = wr[i] * reg[i] + s2;
            float val = qb[o] + s2.x + s2.y;
            dp[d] = val;
            if (which == 1) knorm2 += val * val;
        }
    }
    // this k-row (modality m) feeds attention units with the OTHER modality:
    for (int off = 32; off > 0; off >>= 1)
        knorm2 = fmaxf(knorm2, __shfl_xor(knorm2, off));
    if ((threadIdx.x & 63) == 0) {
        int unit = b * 8 + (1 - m) * 4 + h;
        atomicMax(&kmax2[unit], __float_as_uint(knorm2));
    }
}

// cross-modal attention v9 (kmax^2 input): LDS-staged, NQ=4, bound-max,
// packed fp32, KT=8, atomic accumulation into o1t/o2t/ls.
__global__ __launch_bounds__(256, 2) void cross_attn9_kernel(
    const float* __restrict__ q1, const float* __restrict__ k1, const float* __restrict__ v1,
    const float* __restrict__ q2, const float* __restrict__ k2, const float* __restrict__ v2,
    const unsigned* __restrict__ kmax2, float* __restrict__ ls_glob,
    float* __restrict__ o1t, float* __restrict__ o2t)
{
    int blk  = blockIdx.x;         // 1024 = 128 units * 8 kt
    int kt   = blk & 7;
    int unit = blk >> 3;
    int h = unit & 3;
    int m = (unit >> 2) & 1;
    int b = unit >> 3;
    const float* Q = m ? q2 : q1;
    const float* K = m ? k1 : k2;
    const float* V = m ? v1 : v2;
    const float* Qb = Q + (size_t)(b * 4 + h) * 16384;
    const float* Kb = K + (size_t)(b * 4 + h) * 16384 + kt * 128 * 16;
    const float* Vb = V + (size_t)(b * 4 + h) * 16384 + kt * 128 * 16;
    int tid = threadIdx.x;
    const float SC = 0.25f * 1.44269504088896340736f;
    float km = sqrtf(__uint_as_float(kmax2[unit]));
    v2f qr[4][8], acc[4][8];
    float M[4], ls[4];
#pragma unroll
    for (int j = 0; j < 4; ++j) {
        const v2f* qp = (const v2f*)(Qb + (size_t)(tid + 256 * j) * 16);
        v2f qs2 = {0.f, 0.f};
#pragma unroll
        for (int i = 0; i < 8; ++i) {
            v2f q = qp[i];
            qs2 = q * q + qs2;
            qr[j][i] = q * SC;
        }
        M[j] = sqrtf(qs2.x + qs2.y) * km * SC;
        ls[j] = 0.f;
#pragma unroll
        for (int i = 0; i < 8; ++i) acc[j][i] = (v2f){0.f, 0.f};
    }
    __shared__ float Ks[64 * 16];
    __shared__ float Vs[64 * 16];
    for (int t0 = 0; t0 < 128; t0 += 64) {
        __syncthreads();
        ((float4*)Ks)[tid] = ((const float4*)(Kb + t0 * 16))[tid];
        ((float4*)Vs)[tid] = ((const float4*)(Vb + t0 * 16))[tid];
        __syncthreads();
#pragma unroll 2
        for (int t = 0; t < 64; ++t) {
            const v2f* k2p = (const v2f*)&Ks[t * 16];
            v2f kk[8];
#pragma unroll
            for (int i = 0; i < 8; ++i) kk[i] = k2p[i];
            float p[4];
#pragma unroll
            for (int j = 0; j < 4; ++j) {
                v2f s2 = {0.f, 0.f};
#pragma unroll
                for (int i = 0; i < 8; ++i) s2 = qr[j][i] * kk[i] + s2;
                p[j] = exp2f(s2.x + s2.y - M[j]);
                ls[j] += p[j];
            }
            const v2f* v2p = (const v2f*)&Vs[t * 16];
            v2f vv[8];
#pragma unroll
            for (int i = 0; i < 8; ++i) vv[i] = v2p[i];
#pragma unroll
            for (int j = 0; j < 4; ++j) {
                v2f pj = {p[j], p[j]};
#pragma unroll
                for (int i = 0; i < 8; ++i) acc[j][i] = pj * vv[i] + acc[j][i];
            }
        }
    }
    float* obase = (m ? o2t : o1t) + (size_t)b * 65536 + (size_t)(h * 16) * 1024;
#pragma unroll
    for (int j = 0; j < 4; ++j) {
        int q = tid + 256 * j;
        atomicAdd(&ls_glob[(size_t)unit * 1024 + q], ls[j]);
        float* onum = obase + q;
#pragma unroll
        for (int i = 0; i < 8; ++i) {
            atomicAdd(&onum[(2 * i) * 1024], acc[j][i].x);
            atomicAdd(&onum[(2 * i + 1) * 1024], acc[j][i].y);
        }
    }
}

// output projection with fused 1/ls normalization
__global__ __launch_bounds__(256, 2) void caout3_kernel(const float* __restrict__ o1t,
    const float* __restrict__ o2t, const float* __restrict__ ls_glob,
    const float* __restrict__ ow, const float* __restrict__ ob_,
    float* __restrict__ t1, float* __restrict__ t2)
{
    int blk = blockIdx.x;
    int oc = blk & 1;
    int pc = (blk >> 1) & 3;
    int b  = (blk >> 3) & 15;
    int m  = blk >> 7;
    int l = pc * 256 + threadIdx.x;
    float inv[4];
#pragma unroll
    for (int h = 0; h < 4; ++h)
        inv[h] = 1.f / ls_glob[(size_t)(b * 8 + m * 4 + h) * 1024 + l];
    const float* in = (m ? o2t : o1t) + (size_t)b * 65536 + l;
    v2f reg[32];
#pragma unroll
    for (int i = 0; i < 32; ++i) {
        float iv = inv[i >> 3];
        v2f r; r.x = in[(2 * i) * 1024] * iv; r.y = in[(2 * i + 1) * 1024] * iv;
        reg[i] = r;
    }
    float* t = (m ? t2 : t1) + (size_t)b * 65536 + (size_t)oc * 32 * 1024 + l;
    for (int o = 0; o < 32; ++o) {
        const v2f* wr = (const v2f*)(ow + (oc * 32 + o) * 64);
        v2f s2 = {0.f, 0.f};
#pragma unroll
        for (int i = 0; i < 32; ++i) s2 = wr[i] * reg[i] + s2;
        t[o * 1024] = ob_[oc * 32 + o] + s2.x + s2.y;
    }
}

__global__ __launch_bounds__(256) void final2_kernel(const float* __restrict__ t1,
    const float* __restrict__ t2, const float* __restrict__ chw, const float* __restrict__ spw,
    const float* __restrict__ clsw, const float* __restrict__ clsb, float* __restrict__ out)
{
    int b = blockIdx.x;
    int wave = threadIdx.x >> 6, lane = threadIdx.x & 63;
    __shared__ float feat[64];
    __shared__ float lg[9];
    const float* s1 = spw + b * 1024;
    const float* s2 = spw + 16384 + b * 1024;
    for (int round = 0; round < 16; ++round) {
        int c = round * 4 + wave;
        float g1 = chw[b * 64 + c] + 1.f;
        float g2 = chw[1024 + b * 64 + c] + 1.f;
        const float* p1 = t1 + ((size_t)b * 64 + c) * 1024;
        const float* p2 = t2 + ((size_t)b * 64 + c) * 1024;
        float acc = 0.f;
#pragma unroll
        for (int i = 0; i < 16; ++i) {
            int p = lane + i * 64;
            acc += (g1 + s1[p]) * p1[p] + (g2 + s2[p]) * p2[p];
        }
        for (int off = 32; off > 0; off >>= 1) acc += __shfl_xor(acc, off);
        if (lane == 0) feat[c] = acc * (1.f / 1024.f);
    }
    __syncthreads();
    if (threadIdx.x < 9) {
        int c = threadIdx.x;
        float s = clsb[c];
        for (int i = 0; i < 64; ++i) s += clsw[c * 64 + i] * feat[i];
        lg[c] = s;
    }
    __syncthreads();
    if (threadIdx.x == 0) {
        float mx = -3e38f;
        for (int o = 0; o < 9; ++o) mx = fmaxf(mx, lg[o]);
        float sm = 0.f;
        float e[9];
        for (int o = 0; o < 9; ++o) { e[o] = __expf(lg[o] - mx); sm += e[o]; }
        float inv = 1.f / sm;
        for (int o = 0; o < 9; ++o) out[b * 9 + o] = e[o] * inv;
    }
}

// ---------------------------------------------------------------------------
extern "C" void kernel_launch(void* const* d_in, const int* in_sizes, int n_in,
                              void* d_out, int out_size, void* d_ws, size_t ws_size,
                              hipStream_t stream)
{
    (void)in_sizes; (void)n_in; (void)out_size; (void)ws_size;
    const float* us_input = (const float*)d_in[0];
    const float* img_input = (const float*)d_in[1];
    const float* us_w1 = (const float*)d_in[2];  const float* us_b1 = (const float*)d_in[3];
    const float* us_w2 = (const float*)d_in[4];  const float* us_b2 = (const float*)d_in[5];
    const float* us_w3 = (const float*)d_in[6];  const float* us_b3 = (const float*)d_in[7];
    const float* aff_w = (const float*)d_in[8];  const float* aff_wh = (const float*)d_in[9];
    const float* aff_thr = (const float*)d_in[10];
    const float* img_w1 = (const float*)d_in[11]; const float* img_b1 = (const float*)d_in[12];
    const float* img_w2 = (const float*)d_in[13]; const float* img_b2 = (const float*)d_in[14];
    const float* img_w3 = (const float*)d_in[15]; const float* img_b3 = (const float*)d_in[16];
    const float* db_qkv_w = (const float*)d_in[17]; const float* db_qkv_b = (const float*)d_in[18];
    const float* db_dw_w = (const float*)d_in[19];  const float* db_dw_b = (const float*)d_in[20];
    const float* db_proj_w = (const float*)d_in[21]; const float* db_proj_b = (const float*)d_in[22];
    const float* db_fc_w = (const float*)d_in[23];  const float* db_fc_b = (const float*)d_in[24];
    const float* db_dep_w = (const float*)d_in[25]; const float* db_dep_b = (const float*)d_in[26];
    const float* db_temp = (const float*)d_in[27];
    const float* ca_qkv_w = (const float*)d_in[28]; const float* ca_qkv_b = (const float*)d_in[29];
    const float* ca_out_w = (const float*)d_in[30]; const float* ca_out_b = (const float*)d_in[31];
    const float* tf_ch1_w = (const float*)d_in[32]; const float* tf_ch1_b = (const float*)d_in[33];
    const float* tf_ch2_w = (const float*)d_in[34]; const float* tf_ch2_b = (const float*)d_in[35];
    const float* tf_sp1_w = (const float*)d_in[36]; const float* tf_sp1_b = (const float*)d_in[37];
    const float* tf_sp2_w = (const float*)d_in[38]; const float* tf_sp2_b = (const float*)d_in[39];
    const float* cls_w = (const float*)d_in[40];   const float* cls_b = (const float*)d_in[41];

    float* ws = (float*)d_ws;
    float* us1     = ws + O_SMALL;
    float* us2     = ws + O_SMALL + 1048576;
    float* us3     = ws + O_US3;
    float* xf      = ws + O_XF;
    float* energy  = ws + O_ENERGY;
    float* med     = ws + O_MED;
    float* nrm     = ws + O_NRM;
    float* attn_s  = ws + O_ATTNS;
    float* chpool  = ws + O_CHPOOL;
    float* chw     = ws + O_CHW;
    float* sppool  = ws + O_SPPOOL;
    float* spw     = ws + O_SPW;
    float* qkv     = ws + O_QKV;
    float* qkv_dw  = ws + O_QKVDW;
    float* out_conv= ws + O_OUTCONV;
    float* img1 = ws + O_USFILT;           // O_USFILT region free (us_filt eliminated)
    float* img2 = ws + O_USFILT + 1048576;
    float* y = ws + O_QKVDW;               // dead before dwconv writes qkv_dw
    float* fcv = qkv;                      // qkv dead after dwconv
    float* ca_part = ws + O_SMALL;         // us1/us2 dead after s3; read by merge
    // attention scratch in the dead O_US3 region (us3 consumed by s4):
    float* ca_ls    = ws + O_US3;                    // 131,072 floats
    unsigned* ca_kmax2 = (unsigned*)(ws + O_US3 + 131072);  // 128
    float* us_redT  = ws + O_US3 + 262144;           // 1,048,576 (filled by s7)
    float* img_redT = ws + O_US3 + 1310720;          // 1,048,576 (filled by attnproj)
    float* q1 = ws + O_QKV + CA_Q1 * 1048576;
    float* k1 = ws + O_QKV + CA_K1 * 1048576;
    float* v1 = ws + O_QKV + CA_V1 * 1048576;
    float* q2 = ws + O_QKV + CA_Q2 * 1048576;
    float* k2 = ws + O_QKV + CA_K2 * 1048576;
    float* v2 = ws + O_QKV + CA_V2 * 1048576;
    float* o1t = ws + O_QKV + CA_O1 * 1048576;
    float* o2t = ws + O_QKV + CA_O2 * 1048576;
    float* t1 = ws + O_QKV + CA_T1 * 1048576;
    float* t2 = ws + O_QKV + CA_T2 * 1048576;

    // S1..S3: fused conv stages (US branch || IMG branch)
    s1_kernel<<<1024, 256, 0, stream>>>(us_input, us_w1, us_b1, us1,
                                        img_input, img_w1, img_b1, img1);
    s2_kernel<<<1024, 256, 0, stream>>>(us1, us_w2, us_b2, us2,
                                        img1, img_w2, img_b2, img2);
    s3_kernel<<<1024, 256, 0, stream>>>(us2, us_w3, us_b3, us3,
                                        img2, img_w3, img_b3, y);
    // S4: rfft || qkv 1x1
    s4_kernel<<<2048, 256, 0, stream>>>(us3, xf, y, db_qkv_w, db_qkv_b, qkv);
    // S5: depthwise conv || spectral energy
    s5_kernel<<<49281, 256, 0, stream>>>(qkv, db_dw_w, db_dw_b, qkv_dw, xf, energy);
    // S6: fc || median || chan_attn partials
    s6_kernel<<<4624, 256, 0, stream>>>(qkv_dw, db_fc_w, db_fc_b, fcv, energy, med, ca_part);
    // S7: grouped conv || qknorm || filter+irfft+pool (-> us_redT directly)
    s7_kernel<<<5120, 256, 0, stream>>>(fcv, db_dep_w, db_dep_b, out_conv,
                                        qkv_dw, nrm, xf, energy, med,
                                        aff_w, aff_wh, aff_thr, us_redT);
    // zero attention accumulators (o1t/o2t alias fcv until s7 completes)
    zero_kernel<<<4096, 256, 0, stream>>>(o1t, o2t, ca_ls, ca_kmax2);
    chan_attn_merge_kernel<<<64, 256, 0, stream>>>(ca_part, nrm, db_temp, attn_s);
    // attnproj with fused pooling (-> img_redT directly)
    attnproj_kernel<<<512, 256, 0, stream>>>(attn_s, qkv_dw, out_conv, db_proj_w, db_proj_b, img_redT);
    // caqkv with fused kmax
    caqkv2_kernel<<<512, 256, 0, stream>>>(us_redT, img_redT, ca_qkv_w, ca_qkv_b,
                                           q1, k1, v1, q2, k2, v2, ca_kmax2);
    cross_attn9_kernel<<<1024, 256, 0, stream>>>(q1, k1, v1, q2, k2, v2, ca_kmax2,
                                                 ca_ls, o1t, o2t);
    caout3_kernel<<<256, 256, 0, stream>>>(o1t, o2t, ca_ls, ca_out_w, ca_out_b, t1, t2);
    // S16/S17: fused pooling and gates
    s16_kernel<<<320, 256, 0, stream>>>(t1, t2, chpool, sppool);
    s17_kernel<<<80, 256, 0, stream>>>(sppool, tf_sp1_w, tf_sp1_b, tf_sp2_w, tf_sp2_b, spw,
                                       chpool, tf_ch1_w, tf_ch1_b, tf_ch2_w, tf_ch2_b, chw);
    final2_kernel<<<16, 256, 0, stream>>>(t1, t2, chw, spw, cls_w, cls_b, (float*)d_out);
}

// Round 17
// 858.767 us; speedup vs baseline: 1.0151x; 1.0151x over previous
//
#include <hip/hip_runtime.h>

typedef float v2f __attribute__((ext_vector_type(2)));

// ---------------------------------------------------------------------------
// Workspace layout (float offsets). Total 45,248,512 floats = ~181 MB.
// ---------------------------------------------------------------------------
static constexpr size_t O_SMALL   = 0;
static constexpr size_t O_US3     = 3145728;
static constexpr size_t O_XF      = 7340032;
static constexpr size_t O_USFILT  = 11536384;
static constexpr size_t O_ENERGY  = 15730688;
static constexpr size_t O_MED     = 15764480;
static constexpr size_t O_NRM     = 15765504;
static constexpr size_t O_ATTNS   = 15767552;
static constexpr size_t O_CHPOOL  = 15783936;
static constexpr size_t O_CHW     = 15788032;
static constexpr size_t O_SPPOOL  = 15790080;
static constexpr size_t O_SPW     = 15855616;
static constexpr size_t O_QKV     = 15888384;
static constexpr size_t O_QKVDW   = 28471296;
static constexpr size_t O_OUTCONV = 41054208;
static constexpr size_t CA_Q1 = 2, CA_K1 = 3, CA_V1 = 4,
                        CA_Q2 = 5, CA_K2 = 6, CA_V2 = 7, CA_O1 = 8, CA_O2 = 9,
                        CA_T1 = 10, CA_T2 = 11;

// ===========================================================================
// Device bodies
// ===========================================================================

template<int Ci, int Co>
__device__ __forceinline__ void conv1d3_body(char* smem_raw, int bid,
    const float* __restrict__ in, const float* __restrict__ w,
    const float* __restrict__ bs, float* __restrict__ out)
{
    constexpr int T = 128;
    constexpr int G = 256 / Co;
    constexpr int N = T / G;
    auto lds = (float(*)[T + 2])smem_raw;
    int tid = threadIdx.x;
    int b  = bid >> 5;
    int t0 = (bid & 31) * T;
    const float* inb = in + (size_t)b * Ci * 4096;
    for (int i = tid; i < Ci * T; i += 256) {
        int ci = i / T, x = i % T;
        lds[ci][x + 1] = inb[ci * 4096 + t0 + x];
    }
    if (tid < Ci) {
        lds[tid][0]     = (t0 > 0)        ? inb[tid * 4096 + t0 - 1] : 0.f;
        lds[tid][T + 1] = (t0 + T < 4096) ? inb[tid * 4096 + t0 + T] : 0.f;
    }
    __syncthreads();
    int co = tid / G;
    int x0 = (tid % G) * N;
    float acc[N];
    float bias = bs[co];
#pragma unroll
    for (int j = 0; j < N; ++j) acc[j] = bias;
    const float* wb = w + co * Ci * 3;
    for (int ci = 0; ci < Ci; ++ci) {
        float w0 = wb[ci * 3], w1 = wb[ci * 3 + 1], w2 = wb[ci * 3 + 2];
        float a = lds[ci][x0], bb = lds[ci][x0 + 1];
#pragma unroll
        for (int j = 0; j < N; ++j) {
            float cc = lds[ci][x0 + 2 + j];
            acc[j] += w0 * a + w1 * bb + w2 * cc;
            a = bb; bb = cc;
        }
    }
    float* ob = out + ((size_t)b * Co + co) * 4096 + t0 + x0;
#pragma unroll
    for (int j = 0; j < N; ++j) ob[j] = fmaxf(acc[j], 0.f);
}

template<int Ci, int Co, int TY>
__device__ __forceinline__ void conv2d3_body(char* smem_raw, int bid,
    const float* __restrict__ in, const float* __restrict__ w,
    const float* __restrict__ bs, float* __restrict__ out)
{
    constexpr int G = 256 / (Co * TY);
    constexpr int N = 64 / G;
    auto lds = (float(*)[TY + 2][66])smem_raw;
    int tid = threadIdx.x;
    constexpr int NB = 64 / TY;
    int b  = bid / NB;
    int y0 = (bid % NB) * TY;
    const float* inb = in + (size_t)b * Ci * 4096;
    for (int i = tid; i < Ci * (TY + 2) * 64; i += 256) {
        int x  = i & 63;
        int ry = (i >> 6) % (TY + 2);
        int ci = i / ((TY + 2) * 64);
        int gy = y0 - 1 + ry;
        lds[ci][ry][x + 1] = (gy >= 0 && gy < 64) ? inb[ci * 4096 + gy * 64 + x] : 0.f;
    }
    for (int r = tid; r < Ci * (TY + 2); r += 256) {
        int ry = r % (TY + 2), ci = r / (TY + 2);
        lds[ci][ry][0] = 0.f; lds[ci][ry][65] = 0.f;
    }
    __syncthreads();
    int co   = tid / (TY * G);
    int ysub = (tid / G) % TY;
    int x0   = (tid % G) * N;
    float acc[N];
    float bias = bs[co];
#pragma unroll
    for (int j = 0; j < N; ++j) acc[j] = bias;
    const float* wb = w + co * Ci * 9;
    for (int ci = 0; ci < Ci; ++ci) {
        float wr[9];
#pragma unroll
        for (int k = 0; k < 9; ++k) wr[k] = wb[ci * 9 + k];
#pragma unroll
        for (int dy = 0; dy < 3; ++dy) {
            const float* lr = &lds[ci][ysub + dy][x0];
            float a = lr[0], bb = lr[1];
#pragma unroll
            for (int j = 0; j < N; ++j) {
                float cc = lr[2 + j];
                acc[j] += wr[dy * 3] * a + wr[dy * 3 + 1] * bb + wr[dy * 3 + 2] * cc;
                a = bb; bb = cc;
            }
        }
    }
    float* ob = out + ((size_t)b * Co + co) * 4096 + (y0 + ysub) * 64 + x0;
#pragma unroll
    for (int j = 0; j < N; ++j) ob[j] = fmaxf(acc[j], 0.f);
}

// 4096-pt radix-4 Stockham FFT, SINGLE 32KB LDS buffer.
__device__ __forceinline__ void fft4096_r4_sb(float2* A, int tid)
{
    int Ns = 1;
    for (int s = 0; s < 6; ++s) {
        float cfac = -0.25f / (float)Ns;
        float2 va[4][4];
#pragma unroll
        for (int r = 0; r < 4; ++r) {
            int j = (r << 8) + tid;
            va[r][0] = A[j];
            va[r][1] = A[j + 1024];
            va[r][2] = A[j + 2048];
            va[r][3] = A[j + 3072];
        }
        __syncthreads();
#pragma unroll
        for (int r = 0; r < 4; ++r) {
            int j = (r << 8) + tid;
            int jm = j & (Ns - 1);
            float rev = (float)jm * cfac;
            float s1 = __builtin_amdgcn_sinf(rev);
            float c1 = __builtin_amdgcn_cosf(rev);
            float c2 = c1 * c1 - s1 * s1, s2 = 2.f * c1 * s1;
            float c3 = c2 * c1 - s2 * s1, s3 = c2 * s1 + s2 * c1;
            float2 v0 = va[r][0], v1 = va[r][1], v2 = va[r][2], v3 = va[r][3];
            float2 u1 = make_float2(v1.x * c1 - v1.y * s1, v1.x * s1 + v1.y * c1);
            float2 u2 = make_float2(v2.x * c2 - v2.y * s2, v2.x * s2 + v2.y * c2);
            float2 u3 = make_float2(v3.x * c3 - v3.y * s3, v3.x * s3 + v3.y * c3);
            float t0x = v0.x + u2.x, t0y = v0.y + u2.y;
            float t1x = v0.x - u2.x, t1y = v0.y - u2.y;
            float t2x = u1.x + u3.x, t2y = u1.y + u3.y;
            float t3x = u1.x - u3.x, t3y = u1.y - u3.y;
            int base = ((j - jm) << 2) + jm;
            A[base]          = make_float2(t0x + t2x, t0y + t2y);
            A[base + Ns]     = make_float2(t1x + t3y, t1y - t3x);
            A[base + 2 * Ns] = make_float2(t0x - t2x, t0y - t2y);
            A[base + 3 * Ns] = make_float2(t1x - t3y, t1y + t3x);
        }
        __syncthreads();
        Ns <<= 2;
    }
}

__device__ __forceinline__ void fft_fwd_body(char* smem_raw, int row,
    const float* __restrict__ us3, float* __restrict__ xf)
{
    float2* A = (float2*)smem_raw;
    int tid = threadIdx.x;
    const float* x = us3 + (size_t)row * 4096;
    for (int r = 0; r < 16; ++r) {
        int i = (r << 8) + tid;
        A[i] = make_float2(x[i], 0.f);
    }
    __syncthreads();
    fft4096_r4_sb(A, tid);
    float* out = xf + (size_t)row * 4098;
    for (int r = 0; r < 9; ++r) {
        int f = (r << 8) + tid;
        if (f < 2049) {
            out[2 * f]     = A[f].x * (1.f / 64.f);
            out[2 * f + 1] = A[f].y * (1.f / 64.f);
        }
    }
}

__device__ __forceinline__ void energy_body(int bid,
    const float* __restrict__ xf, float* __restrict__ energy)
{
    int idx = bid * 256 + threadIdx.x;
    if (idx >= 16 * 2049) return;
    int b = idx / 2049, f = idx % 2049;
    const float* p = xf + (size_t)b * 64 * 4098 + 2 * f;
    float e = 0.f;
    for (int ch = 0; ch < 64; ++ch) {
        float re = p[0], im = p[1];
        e += re * re + im * im;
        p += 4098;
    }
    energy[idx] = e;
}

__device__ __forceinline__ void median_body(char* smem_raw, int b,
    const float* __restrict__ energy, float* __restrict__ med)
{
    float* s = (float*)smem_raw;
    int tid = threadIdx.x;
    for (int r = 0; r < 16; ++r) {
        int i = (r << 8) + tid;
        s[i] = (i < 2049) ? energy[b * 2049 + i] : 3.0e38f;
    }
    __syncthreads();
    for (int k = 2; k <= 4096; k <<= 1) {
        for (int j = k >> 1; j > 0; j >>= 1) {
            for (int r = 0; r < 16; ++r) {
                int i = (r << 8) + tid;
                int ixj = i ^ j;
                if (ixj > i) {
                    bool up = ((i & k) == 0);
                    float a = s[i], bb = s[ixj];
                    if ((a > bb) == up) { s[i] = bb; s[ixj] = a; }
                }
            }
            __syncthreads();
        }
    }
    if (tid == 0) med[b] = s[1024];
}

// filter + irfft + FUSED 4:1 adaptive pooling -> us_redT (coalesced stores)
__device__ __forceinline__ void filter_ifft_body(char* smem_raw, int row,
    const float* __restrict__ xf, const float* __restrict__ energy,
    const float* __restrict__ med, const float* __restrict__ aff_w,
    const float* __restrict__ aff_wh, const float* __restrict__ thr_p,
    float* __restrict__ us_redT)
{
    float2* A = (float2*)smem_raw;
    int b = row >> 6, ch = row & 63;
    int tid = threadIdx.x;
    float thr = thr_p[0];
    float mden = med[b] + 1e-6f;
    float w0r = aff_w[2 * ch], w0i = aff_w[2 * ch + 1];
    float whr = aff_wh[2 * ch], whi = aff_wh[2 * ch + 1];
    const float* X = xf + (size_t)row * 4098;
    const float* E = energy + b * 2049;
    for (int r = 0; r < 9; ++r) {
        int f = (r << 8) + tid;
        if (f < 2049) {
            float re = X[2 * f], im = X[2 * f + 1];
            float mask = (E[f] / mden > thr) ? 1.f : 0.f;
            float wr = w0r + mask * whr;
            float wi = w0i + mask * whi;
            float xr = re * wr - im * wi;
            float xi = re * wi + im * wr;
            A[f] = make_float2(xr, -xi);
            if (f >= 1 && f <= 2047) A[4096 - f] = make_float2(xr, xi);
        }
    }
    __syncthreads();
    fft4096_r4_sb(A, tid);
    float* outp = us_redT + (size_t)row * 1024;
    const float SCL = 0.25f * (1.f / 64.f);
#pragma unroll
    for (int r = 0; r < 4; ++r) {
        int s4 = (r << 8) + tid;
        float v = (A[4 * s4].x + A[4 * s4 + 1].x + A[4 * s4 + 2].x + A[4 * s4 + 3].x) * SCL;
        outp[s4] = v;
    }
}

// 1x1 conv 64->192, register-blocked, packed-fp32
__device__ __forceinline__ void qkv1x1_body(int bid, const float* __restrict__ y,
    const float* __restrict__ w, const float* __restrict__ bs, float* __restrict__ out)
{
    int oc = bid & 3;
    int pc = (bid >> 2) & 15;
    int b  = bid >> 6;
    int p = pc * 256 + threadIdx.x;
    const float* inb = y + (size_t)b * 262144 + p;
    v2f reg[32];
#pragma unroll
    for (int ci = 0; ci < 32; ++ci) {
        v2f r; r.x = inb[(2 * ci) * 4096]; r.y = inb[(2 * ci + 1) * 4096];
        reg[ci] = r;
    }
    float* ob = out + (size_t)b * 786432 + (size_t)oc * 48 * 4096 + p;
    for (int o = 0; o < 48; ++o) {
        const v2f* wr = (const v2f*)(w + (oc * 48 + o) * 64);
        v2f s2 = {0.f, 0.f};
#pragma unroll
        for (int ci = 0; ci < 32; ++ci) s2 = wr[ci] * reg[ci] + s2;
        ob[o * 4096] = bs[oc * 48 + o] + s2.x + s2.y;
    }
}

// depthwise 3x3 pad=1, 192 channels
__device__ __forceinline__ void dwconv_body(int bid, const float* __restrict__ in,
    const float* __restrict__ w, const float* __restrict__ bs, float* __restrict__ out)
{
    int idx = bid * 256 + threadIdx.x;
    int x = idx & 63, yy = (idx >> 6) & 63;
    int c = (idx >> 12) % 192;
    const float* p = in + idx;
    const float* wp = w + c * 9;
    float acc = bs[c];
    bool ym = yy > 0, yp = yy < 63, xm = x > 0, xp = x < 63;
    float s = wp[4] * p[0];
    if (ym) { s += wp[1] * p[-64]; if (xm) s += wp[0] * p[-65]; if (xp) s += wp[2] * p[-63]; }
    if (xm) s += wp[3] * p[-1];
    if (xp) s += wp[5] * p[1];
    if (yp) { s += wp[7] * p[64];  if (xm) s += wp[6] * p[63];  if (xp) s += wp[8] * p[65]; }
    out[idx] = acc + s;
}

// fc over the "faithful reshape"
__device__ __forceinline__ void fc_body(int bid, const float* __restrict__ qkv_dw,
    const float* __restrict__ fw, const float* __restrict__ fb, float* __restrict__ fcv)
{
    int idx = bid * 256 + threadIdx.x;
    int k = idx & 15;
    int p = (idx >> 4) & 4095;
    int b = idx >> 16;
    const float* base = qkv_dw + (size_t)b * 786432;
    float u[12];
#pragma unroll
    for (int i = 0; i < 12; ++i) u[i] = base[p * 192 + i * 16 + k];
#pragma unroll
    for (int o = 0; o < 9; ++o) {
        float s = fb[o];
#pragma unroll
        for (int i = 0; i < 12; ++i) s += fw[o * 12 + i] * u[i];
        fcv[(((size_t)b * 16 + k) * 9 + o) * 4096 + p] = s;
    }
}

// grouped conv 144->64 g=16, LDS-tiled (needs 23760 B)
__device__ __forceinline__ void depconv2_body(char* smem_raw, int bid,
    const float* __restrict__ fcv, const float* __restrict__ w,
    const float* __restrict__ bs, float* __restrict__ out)
{
    auto lds = (float(*)[10][66])smem_raw;
    int band = bid & 7;
    int g    = (bid >> 3) & 15;
    int b    = bid >> 7;
    int y0 = band * 8;
    int tid = threadIdx.x;
    const float* inb = fcv + ((size_t)(b * 16 + g) * 9) * 4096;
    for (int i = tid; i < 9 * 10 * 64; i += 256) {
        int x  = i & 63;
        int ry = (i >> 6) % 10;
        int ci = i / 640;
        int gy = y0 - 1 + ry;
        lds[ci][ry][x + 1] = (gy >= 0 && gy < 64) ? inb[ci * 4096 + gy * 64 + x] : 0.f;
    }
    for (int i = tid; i < 90; i += 256) {
        int ry = i % 10, ci = i / 10;
        lds[ci][ry][0] = 0.f; lds[ci][ry][65] = 0.f;
    }
    __syncthreads();
    int co   = tid >> 6;
    int ysub = (tid >> 3) & 7;
    int x0   = (tid & 7) * 8;
    int ocg  = g * 4 + co;
    float acc[8];
    float bias = bs[ocg];
#pragma unroll
    for (int j = 0; j < 8; ++j) acc[j] = bias;
    const float* wb = w + ocg * 81;
    for (int ci = 0; ci < 9; ++ci) {
        float wr[9];
#pragma unroll
        for (int k = 0; k < 9; ++k) wr[k] = wb[ci * 9 + k];
#pragma unroll
        for (int dy = 0; dy < 3; ++dy) {
            const float* lr = &lds[ci][ysub + dy][x0];
            float a = lr[0], bb = lr[1];
#pragma unroll
            for (int j = 0; j < 8; ++j) {
                float cc = lr[2 + j];
                acc[j] += wr[dy * 3] * a + wr[dy * 3 + 1] * bb + wr[dy * 3 + 2] * cc;
                a = bb; bb = cc;
            }
        }
    }
    float* ob = out + ((size_t)b * 64 + ocg) * 4096 + (y0 + ysub) * 64 + x0;
#pragma unroll
    for (int j = 0; j < 8; ++j) ob[j] = acc[j];
}

// L2 norms of q/k rows
__device__ __forceinline__ void qknorm_body(char* smem_raw, int row,
    const float* __restrict__ qkv_dw, float* __restrict__ nrm)
{
    float* red = (float*)smem_raw;
    int which = row >> 10;
    int r = row & 1023;
    int b = r >> 6, hd = r & 63;
    const float* p = qkv_dw + ((size_t)b * 192 + which * 64 + hd) * 4096;
    float s = 0.f;
    for (int i = threadIdx.x; i < 4096; i += 256) { float v = p[i]; s += v * v; }
    red[threadIdx.x] = s;
    __syncthreads();
    for (int st = 128; st > 0; st >>= 1) {
        if (threadIdx.x < st) red[threadIdx.x] += red[threadIdx.x + st];
        __syncthreads();
    }
    if (threadIdx.x == 0) nrm[row] = sqrtf(red[0]);
}

// channel attention partials (arena-based LDS: 16640 B)
__device__ __forceinline__ void chan_attn_part_body(char* smem_raw, int blk,
    const float* __restrict__ qkv_dw, float* __restrict__ part)
{
    auto Qs  = (float(*)[130])smem_raw;
    auto Ks2 = (float(*)[130])(smem_raw + 16 * 130 * 4);
    int nc = blk & 7;
    int bh = blk >> 3;
    int b = bh >> 2, h = bh & 3;
    int c = threadIdx.x >> 4, d = threadIdx.x & 15;
    const float* qbase = qkv_dw + ((size_t)b * 192 + h * 16) * 4096 + nc * 512;
    const float* kbase = qkv_dw + ((size_t)b * 192 + 64 + h * 16) * 4096 + nc * 512;
    float s = 0.f;
    for (int n0 = 0; n0 < 512; n0 += 128) {
        __syncthreads();
        for (int r = 0; r < 8; ++r) {
            int i = (r << 8) + threadIdx.x;
            int row = i >> 7, col = i & 127;
            Qs[row][col]  = qbase[(size_t)row * 4096 + n0 + col];
            Ks2[row][col] = kbase[(size_t)row * 4096 + n0 + col];
        }
        __syncthreads();
#pragma unroll 8
        for (int n = 0; n < 128; ++n) s += Qs[c][n] * Ks2[d][n];
    }
    part[(size_t)blk * 256 + threadIdx.x] = s;
}

// channel pooling (wave-per-row shuffle reduction)
__device__ __forceinline__ void chpool2_body(int bid, const float* __restrict__ t1,
    const float* __restrict__ t2, float* __restrict__ chpool)
{
    int rg = bid & 15;
    int b  = bid >> 4;
    int wave = threadIdx.x >> 6, lane = threadIdx.x & 63;
    int c = rg * 4 + wave;
    const float* p1 = t1 + ((size_t)b * 64 + c) * 1024;
    const float* p2 = t2 + ((size_t)b * 64 + c) * 1024;
    float m1 = 0.f, x1 = -3e38f, m2 = 0.f, x2 = -3e38f;
#pragma unroll
    for (int i = 0; i < 16; ++i) {
        int p = lane + i * 64;
        float a = p1[p], bb = p2[p];
        m1 += a; x1 = fmaxf(x1, a);
        m2 += bb; x2 = fmaxf(x2, bb);
    }
    for (int off = 32; off > 0; off >>= 1) {
        m1 += __shfl_xor(m1, off);
        x1 = fmaxf(x1, __shfl_xor(x1, off));
        m2 += __shfl_xor(m2, off);
        x2 = fmaxf(x2, __shfl_xor(x2, off));
    }
    if (lane == 0) {
        chpool[b * 256 + c]       = m1 * (1.f / 1024.f);
        chpool[b * 256 + 64 + c]  = x1;
        chpool[b * 256 + 128 + c] = m2 * (1.f / 1024.f);
        chpool[b * 256 + 192 + c] = x2;
    }
}

// spatial pooling over channels
__device__ __forceinline__ void sppool_body(int bid, const float* __restrict__ t1,
    const float* __restrict__ t2, float* __restrict__ sppool)
{
    int b = bid >> 2;
    int p = (bid & 3) * 256 + threadIdx.x;
    float m1 = 0.f, x1 = -3e38f, m2 = 0.f, x2 = -3e38f;
    const float* p1 = t1 + (size_t)b * 65536 + p;
    const float* p2 = t2 + (size_t)b * 65536 + p;
    for (int c = 0; c < 64; ++c) {
        float a = p1[c * 1024], bb = p2[c * 1024];
        m1 += a; x1 = fmaxf(x1, a);
        m2 += bb; x2 = fmaxf(x2, bb);
    }
    sppool[b * 4096 + p]        = m1 * (1.f / 64.f);
    sppool[b * 4096 + 1024 + p] = x1;
    sppool[b * 4096 + 2048 + p] = m2 * (1.f / 64.f);
    sppool[b * 4096 + 3072 + p] = x2;
}

// channel gates (first 64 threads active)
__device__ __forceinline__ void chgate_body(int b, const float* __restrict__ chpool,
    const float* __restrict__ w1, const float* __restrict__ b1,
    const float* __restrict__ w2, const float* __restrict__ b2, float* __restrict__ chw)
{
    int c = threadIdx.x;
    if (c >= 64) return;
    float a1 = b1[0], a2 = b2[0];
    for (int ic = 0; ic < 4; ++ic) {
        const float* cp = chpool + b * 256 + ic * 64;
        for (int d = -1; d <= 1; ++d) {
            int cc = c + d;
            if (cc >= 0 && cc < 64) {
                a1 += w1[ic * 3 + d + 1] * cp[cc];
                a2 += w2[ic * 3 + d + 1] * cp[cc];
            }
        }
    }
    float mx = fmaxf(a1, a2);
    float e1 = __expf(a1 - mx), e2 = __expf(a2 - mx);
    float inv = 1.f / (e1 + e2);
    chw[b * 64 + c]        = e1 * inv;
    chw[1024 + b * 64 + c] = e2 * inv;
}

// spatial gates
__device__ __forceinline__ void spgate_body(int bid, const float* __restrict__ sppool,
    const float* __restrict__ w1, const float* __restrict__ b1,
    const float* __restrict__ w2, const float* __restrict__ b2, float* __restrict__ spw)
{
    int idx = bid * 256 + threadIdx.x;
    int p = idx & 1023;
    int b = idx >> 10;
    int y = p >> 5, x = p & 31;
    float a1 = b1[0], a2 = b2[0];
    for (int ic = 0; ic < 4; ++ic) {
        const float* sp = sppool + b * 4096 + ic * 1024;
        for (int dy = -3; dy <= 3; ++dy) {
            int yy = y + dy;
            if (yy < 0 || yy > 31) continue;
            for (int dx = -3; dx <= 3; ++dx) {
                int xx = x + dx;
                if (xx < 0 || xx > 31) continue;
                float v = sp[yy * 32 + xx];
                int wi = ic * 49 + (dy + 3) * 7 + (dx + 3);
                a1 += w1[wi] * v;
                a2 += w2[wi] * v;
            }
        }
    }
    float mx = fmaxf(a1, a2);
    float e1 = __expf(a1 - mx), e2 = __expf(a2 - mx);
    float inv = 1.f / (e1 + e2);
    spw[idx]         = e1 * inv;
    spw[16384 + idx] = e2 * inv;
}

// ===========================================================================
// Fused dispatcher kernels
// ===========================================================================

__global__ __launch_bounds__(256) void s1_kernel(const float* us_in, const float* uw, const float* ub,
    float* uo, const float* iin, const float* iw, const float* ib, float* io)
{
    __shared__ __align__(16) char smem[3168];
    if (blockIdx.x < 512) conv1d3_body<1, 16>(smem, blockIdx.x, us_in, uw, ub, uo);
    else                  conv2d3_body<3, 16, 2>(smem, blockIdx.x - 512, iin, iw, ib, io);
}

__global__ __launch_bounds__(256) void s2_kernel(const float* ui, const float* uw, const float* ub,
    float* uo, const float* ii, const float* iw, const float* ib, float* io)
{
    __shared__ __align__(16) char smem[16896];
    if (blockIdx.x < 512) conv1d3_body<16, 32>(smem, blockIdx.x, ui, uw, ub, uo);
    else                  conv2d3_body<16, 32, 2>(smem, blockIdx.x - 512, ii, iw, ib, io);
}

__global__ __launch_bounds__(256) void s3_kernel(const float* ui, const float* uw, const float* ub,
    float* uo, const float* ii, const float* iw, const float* ib, float* io)
{
    __shared__ __align__(16) char smem[33792];
    if (blockIdx.x < 512) conv1d3_body<32, 64>(smem, blockIdx.x, ui, uw, ub, uo);
    else                  conv2d3_body<32, 64, 2>(smem, blockIdx.x - 512, ii, iw, ib, io);
}

__global__ __launch_bounds__(256) void s4_kernel(const float* us3, float* xf,
    const float* y, const float* qw, const float* qb, float* qkv)
{
    __shared__ __align__(16) char smem[32768];
    if (blockIdx.x < 1024) fft_fwd_body(smem, blockIdx.x, us3, xf);
    else                   qkv1x1_body(blockIdx.x - 1024, y, qw, qb, qkv);
}

__global__ __launch_bounds__(256) void s5_kernel(const float* qkv, const float* dww,
    const float* dwb, float* qkv_dw, const float* xf, float* energy)
{
    if (blockIdx.x < 49152) dwconv_body(blockIdx.x, qkv, dww, dwb, qkv_dw);
    else                    energy_body(blockIdx.x - 49152, xf, energy);
}

// s6: fc || median || chan_attn partials (arena 16640 B)
__global__ __launch_bounds__(256) void s6_kernel(const float* qkv_dw, const float* fw,
    const float* fb, float* fcv, const float* energy, float* med, float* part)
{
    __shared__ __align__(16) char smem[16640];
    if (blockIdx.x < 4096)      fc_body(blockIdx.x, qkv_dw, fw, fb, fcv);
    else if (blockIdx.x < 4112) median_body(smem, blockIdx.x - 4096, energy, med);
    else                        chan_attn_part_body(smem, blockIdx.x - 4112, qkv_dw, part);
}

// s7: depconv || qknorm || filter+irfft+pool (arena 32 KB)
__global__ __launch_bounds__(256) void s7_kernel(const float* fcv, const float* dw,
    const float* db, float* out_conv, const float* qkv_dw, float* nrm,
    const float* xf, const float* energy, const float* med, const float* aw,
    const float* awh, const float* thr, float* us_redT)
{
    __shared__ __align__(16) char smem[32768];
    if (blockIdx.x < 2048)      depconv2_body(smem, blockIdx.x, fcv, dw, db, out_conv);
    else if (blockIdx.x < 4096) qknorm_body(smem, blockIdx.x - 2048, qkv_dw, nrm);
    else                        filter_ifft_body(smem, blockIdx.x - 4096, xf, energy, med, aw, awh, thr, us_redT);
}

// zero o1t/o2t numerators + ls + kmax accumulators
__global__ __launch_bounds__(256) void zero_kernel(float* o1t, float* o2t, float* lsg,
                                                   unsigned* kmax2)
{
    int idx = blockIdx.x * 256 + threadIdx.x;
    if (idx < 1048576) { o1t[idx] = 0.f; o2t[idx] = 0.f; }
    if (idx < 131072) lsg[idx] = 0.f;
    if (idx < 128) kmax2[idx] = 0u;
}

__global__ __launch_bounds__(256) void s16_kernel(const float* t1, const float* t2,
    float* chpool, float* sppool)
{
    if (blockIdx.x < 256) chpool2_body(blockIdx.x, t1, t2, chpool);
    else                  sppool_body(blockIdx.x - 256, t1, t2, sppool);
}

__global__ __launch_bounds__(256) void s17_kernel(const float* sppool, const float* sw1,
    const float* sb1, const float* sw2, const float* sb2, float* spw,
    const float* chpool, const float* cw1, const float* cb1, const float* cw2,
    const float* cb2, float* chw)
{
    if (blockIdx.x < 64) spgate_body(blockIdx.x, sppool, sw1, sb1, sw2, sb2, spw);
    else                 chgate_body(blockIdx.x - 64, chpool, cw1, cb1, cw2, cb2, chw);
}

// chan_attn merge + softmax (64 blocks)
__global__ __launch_bounds__(256) void chan_attn_merge_kernel(
    const float* __restrict__ part, const float* __restrict__ nrm,
    const float* __restrict__ temp, float* __restrict__ attn_s)
{
    int bh = blockIdx.x;
    int b = bh >> 2, h = bh & 3;
    int c = threadIdx.x >> 4, d = threadIdx.x & 15;
    float s = 0.f;
#pragma unroll
    for (int i = 0; i < 8; ++i) s += part[(size_t)(bh * 8 + i) * 256 + threadIdx.x];
    float nq = fmaxf(nrm[b * 64 + h * 16 + c], 1e-12f);
    float nk = fmaxf(nrm[1024 + b * 64 + h * 16 + d], 1e-12f);
    s = s / (nq * nk) * temp[h];
    __shared__ float S[16][17];
    S[c][d] = s;
    __syncthreads();
    if (threadIdx.x < 16) {
        int cc = threadIdx.x;
        float mx = -3e30f;
        for (int dd = 0; dd < 16; ++dd) mx = fmaxf(mx, S[cc][dd]);
        float sm = 0.f;
        float e[16];
        for (int dd = 0; dd < 16; ++dd) { e[dd] = __expf(S[cc][dd] - mx); sm += e[dd]; }
        float inv = 1.f / sm;
        float* dst = attn_s + (size_t)bh * 256 + cc * 16;
        for (int dd = 0; dd < 16; ++dd) dst[dd] = e[dd] * inv;
    }
}

// ===========================================================================
// Standalone kernels
// ===========================================================================

// attn@v + 1x1 proj + out_conv add -> img_feat (full; coalesced stores)
__global__ __launch_bounds__(256, 2) void attnproj_kernel(const float* __restrict__ attn_s,
    const float* __restrict__ qkv_dw, const float* __restrict__ outconv,
    const float* __restrict__ pw, const float* __restrict__ pb, float* __restrict__ img_feat)
{
    int blk = blockIdx.x;
    int oc = blk & 1;
    int pc = (blk >> 1) & 15;
    int b  = blk >> 5;
    int n = pc * 256 + threadIdx.x;
    const float* vb = qkv_dw + ((size_t)b * 192 + 128) * 4096 + n;
    v2f v[32];
#pragma unroll
    for (int i = 0; i < 32; ++i) {
        v2f r; r.x = vb[(2 * i) * 4096]; r.y = vb[(2 * i + 1) * 4096];
        v[i] = r;
    }
    const float* ab = attn_s + (size_t)b * 1024;
    for (int h = 0; h < 4; ++h) {
        v2f tmp[8];
#pragma unroll
        for (int c2 = 0; c2 < 8; ++c2) {
            v2f s2a = {0.f, 0.f}, s2b = {0.f, 0.f};
            const v2f* r0 = (const v2f*)(ab + (h * 16 + 2 * c2) * 16);
            const v2f* r1 = (const v2f*)(ab + (h * 16 + 2 * c2 + 1) * 16);
#pragma unroll
            for (int d2 = 0; d2 < 8; ++d2) {
                s2a = r0[d2] * v[h * 8 + d2] + s2a;
                s2b = r1[d2] * v[h * 8 + d2] + s2b;
            }
            v2f t; t.x = s2a.x + s2a.y; t.y = s2b.x + s2b.y;
            tmp[c2] = t;
        }
#pragma unroll
        for (int c2 = 0; c2 < 8; ++c2) v[h * 8 + c2] = tmp[c2];
    }
    float* ofb = img_feat + (size_t)b * 262144 + (size_t)oc * 32 * 4096 + n;
    const float* ocb = outconv + (size_t)b * 262144 + (size_t)oc * 32 * 4096 + n;
    for (int o = 0; o < 32; ++o) {
        const v2f* wr = (const v2f*)(pw + (oc * 32 + o) * 64);
        v2f s2 = {0.f, 0.f};
#pragma unroll
        for (int c2 = 0; c2 < 32; ++c2) s2 = wr[c2] * v[c2] + s2;
        ofb[o * 4096] = pb[oc * 32 + o] + ocb[o * 4096] + s2.x + s2.y;
    }
}

// 4:1 pool of img_feat -> img_redT (coalesced float4 reads, coalesced stores)
__global__ __launch_bounds__(256) void poolred_img_kernel(const float* __restrict__ img_feat,
    float* __restrict__ img_redT)
{
    int idx = blockIdx.x * 256 + threadIdx.x;   // (b, c, s4), 1,048,576 total
    int s4 = idx & 1023;
    int bc = idx >> 10;
    const float* in = img_feat + (size_t)bc * 4096 + s4 * 4;
    float4 v4 = *(const float4*)in;
    img_redT[(size_t)bc * 1024 + s4] = 0.25f * (v4.x + v4.y + v4.z + v4.w);
}

// shared qkv projection with FUSED kmax (wave-reduced atomicMax of k-norm^2)
__global__ __launch_bounds__(256, 2) void caqkv2_kernel(const float* __restrict__ us_redT,
    const float* __restrict__ img_redT, const float* __restrict__ qw, const float* __restrict__ qb,
    float* __restrict__ q1, float* __restrict__ k1, float* __restrict__ v1,
    float* __restrict__ q2, float* __restrict__ k2, float* __restrict__ v2,
    unsigned* __restrict__ kmax2)
{
    int blk = blockIdx.x;
    int h  = blk & 3;
    int pc = (blk >> 2) & 3;
    int b  = (blk >> 4) & 15;
    int m  = blk >> 8;
    int l = pc * 256 + threadIdx.x;
    const float* in = (m ? img_redT : us_redT) + (size_t)b * 65536 + l;
    v2f reg[32];
#pragma unroll
    for (int i = 0; i < 32; ++i) {
        v2f r; r.x = in[(2 * i) * 1024]; r.y = in[(2 * i + 1) * 1024];
        reg[i] = r;
    }
    size_t rowoff = ((size_t)(b * 4 + h) * 1024 + l) * 16;
    float* dst[3] = { (m ? q2 : q1) + rowoff, (m ? k2 : k1) + rowoff, (m ? v2 : v1) + rowoff };
    float knorm2 = 0.f;
#pragma unroll
    for (int which = 0; which < 3; ++which) {
        float* dp = dst[which];
        for (int d = 0; d < 16; ++d) {
            int o = h * 48 + which * 16 + d;
            const v2f* wr = (const v2f*)(qw + o * 64);
            v2f s2 = {0.f, 0.f};
#pragma unroll
            for (int i = 0; i < 32; ++i) s2 = wr[i] * reg[i] + s2;
            float val = qb[o] + s2.x + s2.y;
            dp[d] = val;
            if (which == 1) knorm2 += val * val;
        }
    }
    for (int off = 32; off > 0; off >>= 1)
        knorm2 = fmaxf(knorm2, __shfl_xor(knorm2, off));
    if ((threadIdx.x & 63) == 0) {
        int unit = b * 8 + (1 - m) * 4 + h;
        atomicMax(&kmax2[unit], __float_as_uint(knorm2));
    }
}

// cross-modal attention v9 (kmax^2 input): LDS-staged, NQ=4, bound-max,
// packed fp32, KT=8, atomic accumulation into o1t/o2t/ls.
__global__ __launch_bounds__(256, 2) void cross_attn9_kernel(
    const float* __restrict__ q1, const float* __restrict__ k1, const float* __restrict__ v1,
    const float* __restrict__ q2, const float* __restrict__ k2, const float* __restrict__ v2,
    const unsigned* __restrict__ kmax2, float* __restrict__ ls_glob,
    float* __restrict__ o1t, float* __restrict__ o2t)
{
    int blk  = blockIdx.x;         // 1024 = 128 units * 8 kt
    int kt   = blk & 7;
    int unit = blk >> 3;
    int h = unit & 3;
    int m = (unit >> 2) & 1;
    int b = unit >> 3;
    const float* Q = m ? q2 : q1;
    const float* K = m ? k1 : k2;
    const float* V = m ? v1 : v2;
    const float* Qb = Q + (size_t)(b * 4 + h) * 16384;
    const float* Kb = K + (size_t)(b * 4 + h) * 16384 + kt * 128 * 16;
    const float* Vb = V + (size_t)(b * 4 + h) * 16384 + kt * 128 * 16;
    int tid = threadIdx.x;
    const float SC = 0.25f * 1.44269504088896340736f;
    float km = sqrtf(__uint_as_float(kmax2[unit]));
    v2f qr[4][8], acc[4][8];
    float M[4], ls[4];
#pragma unroll
    for (int j = 0; j < 4; ++j) {
        const v2f* qp = (const v2f*)(Qb + (size_t)(tid + 256 * j) * 16);
        v2f qs2 = {0.f, 0.f};
#pragma unroll
        for (int i = 0; i < 8; ++i) {
            v2f q = qp[i];
            qs2 = q * q + qs2;
            qr[j][i] = q * SC;
        }
        M[j] = sqrtf(qs2.x + qs2.y) * km * SC;
        ls[j] = 0.f;
#pragma unroll
        for (int i = 0; i < 8; ++i) acc[j][i] = (v2f){0.f, 0.f};
    }
    __shared__ float Ks[64 * 16];
    __shared__ float Vs[64 * 16];
    for (int t0 = 0; t0 < 128; t0 += 64) {
        __syncthreads();
        ((float4*)Ks)[tid] = ((const float4*)(Kb + t0 * 16))[tid];
        ((float4*)Vs)[tid] = ((const float4*)(Vb + t0 * 16))[tid];
        __syncthreads();
#pragma unroll 2
        for (int t = 0; t < 64; ++t) {
            const v2f* k2p = (const v2f*)&Ks[t * 16];
            v2f kk[8];
#pragma unroll
            for (int i = 0; i < 8; ++i) kk[i] = k2p[i];
            float p[4];
#pragma unroll
            for (int j = 0; j < 4; ++j) {
                v2f s2 = {0.f, 0.f};
#pragma unroll
                for (int i = 0; i < 8; ++i) s2 = qr[j][i] * kk[i] + s2;
                p[j] = exp2f(s2.x + s2.y - M[j]);
                ls[j] += p[j];
            }
            const v2f* v2p = (const v2f*)&Vs[t * 16];
            v2f vv[8];
#pragma unroll
            for (int i = 0; i < 8; ++i) vv[i] = v2p[i];
#pragma unroll
            for (int j = 0; j < 4; ++j) {
                v2f pj = {p[j], p[j]};
#pragma unroll
                for (int i = 0; i < 8; ++i) acc[j][i] = pj * vv[i] + acc[j][i];
            }
        }
    }
    float* obase = (m ? o2t : o1t) + (size_t)b * 65536 + (size_t)(h * 16) * 1024;
#pragma unroll
    for (int j = 0; j < 4; ++j) {
        int q = tid + 256 * j;
        atomicAdd(&ls_glob[(size_t)unit * 1024 + q], ls[j]);
        float* onum = obase + q;
#pragma unroll
        for (int i = 0; i < 8; ++i) {
            atomicAdd(&onum[(2 * i) * 1024], acc[j][i].x);
            atomicAdd(&onum[(2 * i + 1) * 1024], acc[j][i].y);
        }
    }
}

// output projection with fused 1/ls normalization
__global__ __launch_bounds__(256, 2) void caout3_kernel(const float* __restrict__ o1t,
    const float* __restrict__ o2t, const float* __restrict__ ls_glob,
    const float* __restrict__ ow, const float* __restrict__ ob_,
    float* __restrict__ t1, float* __restrict__ t2)
{
    int blk = blockIdx.x;
    int oc = blk & 1;
    int pc = (blk >> 1) & 3;
    int b  = (blk >> 3) & 15;
    int m  = blk >> 7;
    int l = pc * 256 + threadIdx.x;
    float inv[4];
#pragma unroll
    for (int h = 0; h < 4; ++h)
        inv[h] = 1.f / ls_glob[(size_t)(b * 8 + m * 4 + h) * 1024 + l];
    const float* in = (m ? o2t : o1t) + (size_t)b * 65536 + l;
    v2f reg[32];
#pragma unroll
    for (int i = 0; i < 32; ++i) {
        float iv = inv[i >> 3];
        v2f r; r.x = in[(2 * i) * 1024] * iv; r.y = in[(2 * i + 1) * 1024] * iv;
        reg[i] = r;
    }
    float* t = (m ? t2 : t1) + (size_t)b * 65536 + (size_t)oc * 32 * 1024 + l;
    for (int o = 0; o < 32; ++o) {
        const v2f* wr = (const v2f*)(ow + (oc * 32 + o) * 64);
        v2f s2 = {0.f, 0.f};
#pragma unroll
        for (int i = 0; i < 32; ++i) s2 = wr[i] * reg[i] + s2;
        t[o * 1024] = ob_[oc * 32 + o] + s2.x + s2.y;
    }
}

__global__ __launch_bounds__(256) void final2_kernel(const float* __restrict__ t1,
    const float* __restrict__ t2, const float* __restrict__ chw, const float* __restrict__ spw,
    const float* __restrict__ clsw, const float* __restrict__ clsb, float* __restrict__ out)
{
    int b = blockIdx.x;
    int wave = threadIdx.x >> 6, lane = threadIdx.x & 63;
    __shared__ float feat[64];
    __shared__ float lg[9];
    const float* s1 = spw + b * 1024;
    const float* s2 = spw + 16384 + b * 1024;
    for (int round = 0; round < 16; ++round) {
        int c = round * 4 + wave;
        float g1 = chw[b * 64 + c] + 1.f;
        float g2 = chw[1024 + b * 64 + c] + 1.f;
        const float* p1 = t1 + ((size_t)b * 64 + c) * 1024;
        const float* p2 = t2 + ((size_t)b * 64 + c) * 1024;
        float acc = 0.f;
#pragma unroll
        for (int i = 0; i < 16; ++i) {
            int p = lane + i * 64;
            acc += (g1 + s1[p]) * p1[p] + (g2 + s2[p]) * p2[p];
        }
        for (int off = 32; off > 0; off >>= 1) acc += __shfl_xor(acc, off);
        if (lane == 0) feat[c] = acc * (1.f / 1024.f);
    }
    __syncthreads();
    if (threadIdx.x < 9) {
        int c = threadIdx.x;
        float s = clsb[c];
        for (int i = 0; i < 64; ++i) s += clsw[c * 64 + i] * feat[i];
        lg[c] = s;
    }
    __syncthreads();
    if (threadIdx.x == 0) {
        float mx = -3e38f;
        for (int o = 0; o < 9; ++o) mx = fmaxf(mx, lg[o]);
        float sm = 0.f;
        float e[9];
        for (int o = 0; o < 9; ++o) { e[o] = __expf(lg[o] - mx); sm += e[o]; }
        float inv = 1.f / sm;
        for (int o = 0; o < 9; ++o) out[b * 9 + o] = e[o] * inv;
    }
}

// ---------------------------------------------------------------------------
extern "C" void kernel_launch(void* const* d_in, const int* in_sizes, int n_in,
                              void* d_out, int out_size, void* d_ws, size_t ws_size,
                              hipStream_t stream)
{
    (void)in_sizes; (void)n_in; (void)out_size; (void)ws_size;
    const float* us_input = (const float*)d_in[0];
    const float* img_input = (const float*)d_in[1];
    const float* us_w1 = (const float*)d_in[2];  const float* us_b1 = (const float*)d_in[3];
    const float* us_w2 = (const float*)d_in[4];  const float* us_b2 = (const float*)d_in[5];
    const float* us_w3 = (const float*)d_in[6];  const float* us_b3 = (const float*)d_in[7];
    const float* aff_w = (const float*)d_in[8];  const float* aff_wh = (const float*)d_in[9];
    const float* aff_thr = (const float*)d_in[10];
    const float* img_w1 = (const float*)d_in[11]; const float* img_b1 = (const float*)d_in[12];
    const float* img_w2 = (const float*)d_in[13]; const float* img_b2 = (const float*)d_in[14];
    const float* img_w3 = (const float*)d_in[15]; const float* img_b3 = (const float*)d_in[16];
    const float* db_qkv_w = (const float*)d_in[17]; const float* db_qkv_b = (const float*)d_in[18];
    const float* db_dw_w = (const float*)d_in[19];  const float* db_dw_b = (const float*)d_in[20];
    const float* db_proj_w = (const float*)d_in[21]; const float* db_proj_b = (const float*)d_in[22];
    const float* db_fc_w = (const float*)d_in[23];  const float* db_fc_b = (const float*)d_in[24];
    const float* db_dep_w = (const float*)d_in[25]; const float* db_dep_b = (const float*)d_in[26];
    const float* db_temp = (const float*)d_in[27];
    const float* ca_qkv_w = (const float*)d_in[28]; const float* ca_qkv_b = (const float*)d_in[29];
    const float* ca_out_w = (const float*)d_in[30]; const float* ca_out_b = (const float*)d_in[31];
    const float* tf_ch1_w = (const float*)d_in[32]; const float* tf_ch1_b = (const float*)d_in[33];
    const float* tf_ch2_w = (const float*)d_in[34]; const float* tf_ch2_b = (const float*)d_in[35];
    const float* tf_sp1_w = (const float*)d_in[36]; const float* tf_sp1_b = (const float*)d_in[37];
    const float* tf_sp2_w = (const float*)d_in[38]; const float* tf_sp2_b = (const float*)d_in[39];
    const float* cls_w = (const float*)d_in[40];   const float* cls_b = (const float*)d_in[41];

    float* ws = (float*)d_ws;
    float* us1     = ws + O_SMALL;
    float* us2     = ws + O_SMALL + 1048576;
    float* us3     = ws + O_US3;
    float* xf      = ws + O_XF;
    float* energy  = ws + O_ENERGY;
    float* med     = ws + O_MED;
    float* nrm     = ws + O_NRM;
    float* attn_s  = ws + O_ATTNS;
    float* chpool  = ws + O_CHPOOL;
    float* chw     = ws + O_CHW;
    float* sppool  = ws + O_SPPOOL;
    float* spw     = ws + O_SPW;
    float* qkv     = ws + O_QKV;
    float* qkv_dw  = ws + O_QKVDW;
    float* out_conv= ws + O_OUTCONV;
    float* img1 = ws + O_USFILT;           // O_USFILT region free (us_filt eliminated)
    float* img2 = ws + O_USFILT + 1048576;
    float* y = ws + O_QKVDW;               // dead before dwconv writes qkv_dw
    float* fcv = qkv;                      // qkv dead after dwconv
    float* img_feat = xf;                  // xf dead after s7's filt branch
    float* ca_part = ws + O_SMALL;         // us1/us2 dead after s3; read by merge
    // attention scratch in the dead O_US3 region (us3 consumed by s4):
    float* ca_ls    = ws + O_US3;                    // 131,072 floats
    unsigned* ca_kmax2 = (unsigned*)(ws + O_US3 + 131072);  // 128
    float* us_redT  = ws + O_US3 + 262144;           // 1,048,576 (filled by s7)
    float* img_redT = ws + O_US3 + 1310720;          // 1,048,576 (filled by poolred_img)
    float* q1 = ws + O_QKV + CA_Q1 * 1048576;
    float* k1 = ws + O_QKV + CA_K1 * 1048576;
    float* v1 = ws + O_QKV + CA_V1 * 1048576;
    float* q2 = ws + O_QKV + CA_Q2 * 1048576;
    float* k2 = ws + O_QKV + CA_K2 * 1048576;
    float* v2 = ws + O_QKV + CA_V2 * 1048576;
    float* o1t = ws + O_QKV + CA_O1 * 1048576;
    float* o2t = ws + O_QKV + CA_O2 * 1048576;
    float* t1 = ws + O_QKV + CA_T1 * 1048576;
    float* t2 = ws + O_QKV + CA_T2 * 1048576;

    // S1..S3: fused conv stages (US branch || IMG branch)
    s1_kernel<<<1024, 256, 0, stream>>>(us_input, us_w1, us_b1, us1,
                                        img_input, img_w1, img_b1, img1);
    s2_kernel<<<1024, 256, 0, stream>>>(us1, us_w2, us_b2, us2,
                                        img1, img_w2, img_b2, img2);
    s3_kernel<<<1024, 256, 0, stream>>>(us2, us_w3, us_b3, us3,
                                        img2, img_w3, img_b3, y);
    // S4: rfft || qkv 1x1
    s4_kernel<<<2048, 256, 0, stream>>>(us3, xf, y, db_qkv_w, db_qkv_b, qkv);
    // S5: depthwise conv || spectral energy
    s5_kernel<<<49281, 256, 0, stream>>>(qkv, db_dw_w, db_dw_b, qkv_dw, xf, energy);
    // S6: fc || median || chan_attn partials
    s6_kernel<<<4624, 256, 0, stream>>>(qkv_dw, db_fc_w, db_fc_b, fcv, energy, med, ca_part);
    // S7: grouped conv || qknorm || filter+irfft+pool (-> us_redT directly)
    s7_kernel<<<5120, 256, 0, stream>>>(fcv, db_dep_w, db_dep_b, out_conv,
                                        qkv_dw, nrm, xf, energy, med,
                                        aff_w, aff_wh, aff_thr, us_redT);
    // zero attention accumulators
    zero_kernel<<<4096, 256, 0, stream>>>(o1t, o2t, ca_ls, ca_kmax2);
    chan_attn_merge_kernel<<<64, 256, 0, stream>>>(ca_part, nrm, db_temp, attn_s);
    // attnproj: full img_feat (coalesced stores), then coalesced 4:1 pool
    attnproj_kernel<<<512, 256, 0, stream>>>(attn_s, qkv_dw, out_conv, db_proj_w, db_proj_b, img_feat);
    poolred_img_kernel<<<4096, 256, 0, stream>>>(img_feat, img_redT);
    // caqkv with fused kmax
    caqkv2_kernel<<<512, 256, 0, stream>>>(us_redT, img_redT, ca_qkv_w, ca_qkv_b,
                                           q1, k1, v1, q2, k2, v2, ca_kmax2);
    cross_attn9_kernel<<<1024, 256, 0, stream>>>(q1, k1, v1, q2, k2, v2, ca_kmax2,
                                                 ca_ls, o1t, o2t);
    caout3_kernel<<<256, 256, 0, stream>>>(o1t, o2t, ca_ls, ca_out_w, ca_out_b, t1, t2);
    // S16/S17: fused pooling and gates
    s16_kernel<<<320, 256, 0, stream>>>(t1, t2, chpool, sppool);
    s17_kernel<<<80, 256, 0, stream>>>(sppool, tf_sp1_w, tf_sp1_b, tf_sp2_w, tf_sp2_b, spw,
                                       chpool, tf_ch1_w, tf_ch1_b, tf_ch2_w, tf_ch2_b, chw);
    final2_kernel<<<16, 256, 0, stream>>>(t1, t2, chw, spw, cls_w, cls_b, (float*)d_out);
}

// Round 18
// 832.394 us; speedup vs baseline: 1.0472x; 1.0317x over previous
//
#include <hip/hip_runtime.h>

typedef float v2f __attribute__((ext_vector_type(2)));

// ---------------------------------------------------------------------------
// Workspace layout (float offsets). Total 45,248,512 floats = ~181 MB.
// ---------------------------------------------------------------------------
static constexpr size_t O_SMALL   = 0;
static constexpr size_t O_US3     = 3145728;
static constexpr size_t O_XF      = 7340032;
static constexpr size_t O_USFILT  = 11536384;
static constexpr size_t O_ENERGY  = 15730688;
static constexpr size_t O_MED     = 15764480;
static constexpr size_t O_NRM     = 15765504;
static constexpr size_t O_ATTNS   = 15767552;
static constexpr size_t O_CHPOOL  = 15783936;
static constexpr size_t O_CHW     = 15788032;
static constexpr size_t O_SPPOOL  = 15790080;
static constexpr size_t O_SPW     = 15855616;
static constexpr size_t O_QKV     = 15888384;
static constexpr size_t O_QKVDW   = 28471296;
static constexpr size_t O_OUTCONV = 41054208;
static constexpr size_t CA_Q1 = 2, CA_K1 = 3, CA_V1 = 4,
                        CA_Q2 = 5, CA_K2 = 6, CA_V2 = 7, CA_O1 = 8, CA_O2 = 9,
                        CA_T1 = 10, CA_T2 = 11;

// ===========================================================================
// Device bodies
// ===========================================================================

template<int Ci, int Co>
__device__ __forceinline__ void conv1d3_body(char* smem_raw, int bid,
    const float* __restrict__ in, const float* __restrict__ w,
    const float* __restrict__ bs, float* __restrict__ out)
{
    constexpr int T = 128;
    constexpr int G = 256 / Co;
    constexpr int N = T / G;
    auto lds = (float(*)[T + 2])smem_raw;
    int tid = threadIdx.x;
    int b  = bid >> 5;
    int t0 = (bid & 31) * T;
    const float* inb = in + (size_t)b * Ci * 4096;
    for (int i = tid; i < Ci * T; i += 256) {
        int ci = i / T, x = i % T;
        lds[ci][x + 1] = inb[ci * 4096 + t0 + x];
    }
    if (tid < Ci) {
        lds[tid][0]     = (t0 > 0)        ? inb[tid * 4096 + t0 - 1] : 0.f;
        lds[tid][T + 1] = (t0 + T < 4096) ? inb[tid * 4096 + t0 + T] : 0.f;
    }
    __syncthreads();
    int co = tid / G;
    int x0 = (tid % G) * N;
    float acc[N];
    float bias = bs[co];
#pragma unroll
    for (int j = 0; j < N; ++j) acc[j] = bias;
    const float* wb = w + co * Ci * 3;
    for (int ci = 0; ci < Ci; ++ci) {
        float w0 = wb[ci * 3], w1 = wb[ci * 3 + 1], w2 = wb[ci * 3 + 2];
        float a = lds[ci][x0], bb = lds[ci][x0 + 1];
#pragma unroll
        for (int j = 0; j < N; ++j) {
            float cc = lds[ci][x0 + 2 + j];
            acc[j] += w0 * a + w1 * bb + w2 * cc;
            a = bb; bb = cc;
        }
    }
    float* ob = out + ((size_t)b * Co + co) * 4096 + t0 + x0;
#pragma unroll
    for (int j = 0; j < N; ++j) ob[j] = fmaxf(acc[j], 0.f);
}

template<int Ci, int Co, int TY>
__device__ __forceinline__ void conv2d3_body(char* smem_raw, int bid,
    const float* __restrict__ in, const float* __restrict__ w,
    const float* __restrict__ bs, float* __restrict__ out)
{
    constexpr int G = 256 / (Co * TY);
    constexpr int N = 64 / G;
    auto lds = (float(*)[TY + 2][66])smem_raw;
    int tid = threadIdx.x;
    constexpr int NB = 64 / TY;
    int b  = bid / NB;
    int y0 = (bid % NB) * TY;
    const float* inb = in + (size_t)b * Ci * 4096;
    for (int i = tid; i < Ci * (TY + 2) * 64; i += 256) {
        int x  = i & 63;
        int ry = (i >> 6) % (TY + 2);
        int ci = i / ((TY + 2) * 64);
        int gy = y0 - 1 + ry;
        lds[ci][ry][x + 1] = (gy >= 0 && gy < 64) ? inb[ci * 4096 + gy * 64 + x] : 0.f;
    }
    for (int r = tid; r < Ci * (TY + 2); r += 256) {
        int ry = r % (TY + 2), ci = r / (TY + 2);
        lds[ci][ry][0] = 0.f; lds[ci][ry][65] = 0.f;
    }
    __syncthreads();
    int co   = tid / (TY * G);
    int ysub = (tid / G) % TY;
    int x0   = (tid % G) * N;
    float acc[N];
    float bias = bs[co];
#pragma unroll
    for (int j = 0; j < N; ++j) acc[j] = bias;
    const float* wb = w + co * Ci * 9;
    for (int ci = 0; ci < Ci; ++ci) {
        float wr[9];
#pragma unroll
        for (int k = 0; k < 9; ++k) wr[k] = wb[ci * 9 + k];
#pragma unroll
        for (int dy = 0; dy < 3; ++dy) {
            const float* lr = &lds[ci][ysub + dy][x0];
            float a = lr[0], bb = lr[1];
#pragma unroll
            for (int j = 0; j < N; ++j) {
                float cc = lr[2 + j];
                acc[j] += wr[dy * 3] * a + wr[dy * 3 + 1] * bb + wr[dy * 3 + 2] * cc;
                a = bb; bb = cc;
            }
        }
    }
    float* ob = out + ((size_t)b * Co + co) * 4096 + (y0 + ysub) * 64 + x0;
#pragma unroll
    for (int j = 0; j < N; ++j) ob[j] = fmaxf(acc[j], 0.f);
}

// 4096-pt radix-4 Stockham FFT, SINGLE 32KB LDS buffer.
__device__ __forceinline__ void fft4096_r4_sb(float2* A, int tid)
{
    int Ns = 1;
    for (int s = 0; s < 6; ++s) {
        float cfac = -0.25f / (float)Ns;
        float2 va[4][4];
#pragma unroll
        for (int r = 0; r < 4; ++r) {
            int j = (r << 8) + tid;
            va[r][0] = A[j];
            va[r][1] = A[j + 1024];
            va[r][2] = A[j + 2048];
            va[r][3] = A[j + 3072];
        }
        __syncthreads();
#pragma unroll
        for (int r = 0; r < 4; ++r) {
            int j = (r << 8) + tid;
            int jm = j & (Ns - 1);
            float rev = (float)jm * cfac;
            float s1 = __builtin_amdgcn_sinf(rev);
            float c1 = __builtin_amdgcn_cosf(rev);
            float c2 = c1 * c1 - s1 * s1, s2 = 2.f * c1 * s1;
            float c3 = c2 * c1 - s2 * s1, s3 = c2 * s1 + s2 * c1;
            float2 v0 = va[r][0], v1 = va[r][1], v2 = va[r][2], v3 = va[r][3];
            float2 u1 = make_float2(v1.x * c1 - v1.y * s1, v1.x * s1 + v1.y * c1);
            float2 u2 = make_float2(v2.x * c2 - v2.y * s2, v2.x * s2 + v2.y * c2);
            float2 u3 = make_float2(v3.x * c3 - v3.y * s3, v3.x * s3 + v3.y * c3);
            float t0x = v0.x + u2.x, t0y = v0.y + u2.y;
            float t1x = v0.x - u2.x, t1y = v0.y - u2.y;
            float t2x = u1.x + u3.x, t2y = u1.y + u3.y;
            float t3x = u1.x - u3.x, t3y = u1.y - u3.y;
            int base = ((j - jm) << 2) + jm;
            A[base]          = make_float2(t0x + t2x, t0y + t2y);
            A[base + Ns]     = make_float2(t1x + t3y, t1y - t3x);
            A[base + 2 * Ns] = make_float2(t0x - t2x, t0y - t2y);
            A[base + 3 * Ns] = make_float2(t1x - t3y, t1y + t3x);
        }
        __syncthreads();
        Ns <<= 2;
    }
}

__device__ __forceinline__ void fft_fwd_body(char* smem_raw, int row,
    const float* __restrict__ us3, float* __restrict__ xf)
{
    float2* A = (float2*)smem_raw;
    int tid = threadIdx.x;
    const float* x = us3 + (size_t)row * 4096;
    for (int r = 0; r < 16; ++r) {
        int i = (r << 8) + tid;
        A[i] = make_float2(x[i], 0.f);
    }
    __syncthreads();
    fft4096_r4_sb(A, tid);
    float* out = xf + (size_t)row * 4098;
    for (int r = 0; r < 9; ++r) {
        int f = (r << 8) + tid;
        if (f < 2049) {
            out[2 * f]     = A[f].x * (1.f / 64.f);
            out[2 * f + 1] = A[f].y * (1.f / 64.f);
        }
    }
}

__device__ __forceinline__ void energy_body(int bid,
    const float* __restrict__ xf, float* __restrict__ energy)
{
    int idx = bid * 256 + threadIdx.x;
    if (idx >= 16 * 2049) return;
    int b = idx / 2049, f = idx % 2049;
    const float* p = xf + (size_t)b * 64 * 4098 + 2 * f;
    float e = 0.f;
    for (int ch = 0; ch < 64; ++ch) {
        float re = p[0], im = p[1];
        e += re * re + im * im;
        p += 4098;
    }
    energy[idx] = e;
}

__device__ __forceinline__ void median_body(char* smem_raw, int b,
    const float* __restrict__ energy, float* __restrict__ med)
{
    float* s = (float*)smem_raw;
    int tid = threadIdx.x;
    for (int r = 0; r < 16; ++r) {
        int i = (r << 8) + tid;
        s[i] = (i < 2049) ? energy[b * 2049 + i] : 3.0e38f;
    }
    __syncthreads();
    for (int k = 2; k <= 4096; k <<= 1) {
        for (int j = k >> 1; j > 0; j >>= 1) {
            for (int r = 0; r < 16; ++r) {
                int i = (r << 8) + tid;
                int ixj = i ^ j;
                if (ixj > i) {
                    bool up = ((i & k) == 0);
                    float a = s[i], bb = s[ixj];
                    if ((a > bb) == up) { s[i] = bb; s[ixj] = a; }
                }
            }
            __syncthreads();
        }
    }
    if (tid == 0) med[b] = s[1024];
}

// filter + irfft + FUSED 4:1 adaptive pooling -> us_redT (coalesced stores)
__device__ __forceinline__ void filter_ifft_body(char* smem_raw, int row,
    const float* __restrict__ xf, const float* __restrict__ energy,
    const float* __restrict__ med, const float* __restrict__ aff_w,
    const float* __restrict__ aff_wh, const float* __restrict__ thr_p,
    float* __restrict__ us_redT)
{
    float2* A = (float2*)smem_raw;
    int b = row >> 6, ch = row & 63;
    int tid = threadIdx.x;
    float thr = thr_p[0];
    float mden = med[b] + 1e-6f;
    float w0r = aff_w[2 * ch], w0i = aff_w[2 * ch + 1];
    float whr = aff_wh[2 * ch], whi = aff_wh[2 * ch + 1];
    const float* X = xf + (size_t)row * 4098;
    const float* E = energy + b * 2049;
    for (int r = 0; r < 9; ++r) {
        int f = (r << 8) + tid;
        if (f < 2049) {
            float re = X[2 * f], im = X[2 * f + 1];
            float mask = (E[f] / mden > thr) ? 1.f : 0.f;
            float wr = w0r + mask * whr;
            float wi = w0i + mask * whi;
            float xr = re * wr - im * wi;
            float xi = re * wi + im * wr;
            A[f] = make_float2(xr, -xi);
            if (f >= 1 && f <= 2047) A[4096 - f] = make_float2(xr, xi);
        }
    }
    __syncthreads();
    fft4096_r4_sb(A, tid);
    float* outp = us_redT + (size_t)row * 1024;
    const float SCL = 0.25f * (1.f / 64.f);
#pragma unroll
    for (int r = 0; r < 4; ++r) {
        int s4 = (r << 8) + tid;
        float v = (A[4 * s4].x + A[4 * s4 + 1].x + A[4 * s4 + 2].x + A[4 * s4 + 3].x) * SCL;
        outp[s4] = v;
    }
}

// 1x1 conv 64->192, register-blocked, packed-fp32
__device__ __forceinline__ void qkv1x1_body(int bid, const float* __restrict__ y,
    const float* __restrict__ w, const float* __restrict__ bs, float* __restrict__ out)
{
    int oc = bid & 3;
    int pc = (bid >> 2) & 15;
    int b  = bid >> 6;
    int p = pc * 256 + threadIdx.x;
    const float* inb = y + (size_t)b * 262144 + p;
    v2f reg[32];
#pragma unroll
    for (int ci = 0; ci < 32; ++ci) {
        v2f r; r.x = inb[(2 * ci) * 4096]; r.y = inb[(2 * ci + 1) * 4096];
        reg[ci] = r;
    }
    float* ob = out + (size_t)b * 786432 + (size_t)oc * 48 * 4096 + p;
    for (int o = 0; o < 48; ++o) {
        const v2f* wr = (const v2f*)(w + (oc * 48 + o) * 64);
        v2f s2 = {0.f, 0.f};
#pragma unroll
        for (int ci = 0; ci < 32; ++ci) s2 = wr[ci] * reg[ci] + s2;
        ob[o * 4096] = bs[oc * 48 + o] + s2.x + s2.y;
    }
}

// depthwise 3x3 pad=1, 192 channels, LDS-tiled: block = one (b,c) plane.
// Loads the 64x64 plane + halo into 66x66 LDS once (coalesced), then each
// thread computes 16 outputs via sliding-window registers.
__device__ __forceinline__ void dwconv2_body(char* smem_raw, int bid,
    const float* __restrict__ in, const float* __restrict__ w,
    const float* __restrict__ bs, float* __restrict__ out)
{
    auto lds = (float(*)[66])smem_raw;   // [66][66]
    int c = bid % 192;
    int b = bid / 192;
    int tid = threadIdx.x;
    const float* inb = in + ((size_t)b * 192 + c) * 4096;
    // interior rows (66 rows x 64 cols), coalesced 64-wide
    for (int i = tid; i < 66 * 64; i += 256) {
        int col = i & 63;
        int row = i >> 6;            // 0..65 -> gy = row-1
        int gy = row - 1;
        lds[row][col + 1] = (gy >= 0 && gy < 64) ? inb[gy * 64 + col] : 0.f;
    }
    // side pads
    for (int r = tid; r < 66; r += 256) { lds[r][0] = 0.f; lds[r][65] = 0.f; }
    __syncthreads();
    float wr[9];
#pragma unroll
    for (int k = 0; k < 9; ++k) wr[k] = w[c * 9 + k];
    float bias = bs[c];
    int y  = tid >> 2;               // 64 rows, 4 threads/row
    int x0 = (tid & 3) * 16;         // 16 consecutive cols each
    float acc[16];
#pragma unroll
    for (int j = 0; j < 16; ++j) acc[j] = bias;
#pragma unroll
    for (int dy = 0; dy < 3; ++dy) {
        const float* lr = &lds[y + dy][x0];
        float a = lr[0], bb = lr[1];
#pragma unroll
        for (int j = 0; j < 16; ++j) {
            float cc = lr[2 + j];
            acc[j] += wr[dy * 3] * a + wr[dy * 3 + 1] * bb + wr[dy * 3 + 2] * cc;
            a = bb; bb = cc;
        }
    }
    float* ob = out + ((size_t)b * 192 + c) * 4096 + y * 64 + x0;
#pragma unroll
    for (int j = 0; j < 16; ++j) ob[j] = acc[j];
}

// fc over the "faithful reshape"
__device__ __forceinline__ void fc_body(int bid, const float* __restrict__ qkv_dw,
    const float* __restrict__ fw, const float* __restrict__ fb, float* __restrict__ fcv)
{
    int idx = bid * 256 + threadIdx.x;
    int k = idx & 15;
    int p = (idx >> 4) & 4095;
    int b = idx >> 16;
    const float* base = qkv_dw + (size_t)b * 786432;
    float u[12];
#pragma unroll
    for (int i = 0; i < 12; ++i) u[i] = base[p * 192 + i * 16 + k];
#pragma unroll
    for (int o = 0; o < 9; ++o) {
        float s = fb[o];
#pragma unroll
        for (int i = 0; i < 12; ++i) s += fw[o * 12 + i] * u[i];
        fcv[(((size_t)b * 16 + k) * 9 + o) * 4096 + p] = s;
    }
}

// grouped conv 144->64 g=16, LDS-tiled (needs 23760 B)
__device__ __forceinline__ void depconv2_body(char* smem_raw, int bid,
    const float* __restrict__ fcv, const float* __restrict__ w,
    const float* __restrict__ bs, float* __restrict__ out)
{
    auto lds = (float(*)[10][66])smem_raw;
    int band = bid & 7;
    int g    = (bid >> 3) & 15;
    int b    = bid >> 7;
    int y0 = band * 8;
    int tid = threadIdx.x;
    const float* inb = fcv + ((size_t)(b * 16 + g) * 9) * 4096;
    for (int i = tid; i < 9 * 10 * 64; i += 256) {
        int x  = i & 63;
        int ry = (i >> 6) % 10;
        int ci = i / 640;
        int gy = y0 - 1 + ry;
        lds[ci][ry][x + 1] = (gy >= 0 && gy < 64) ? inb[ci * 4096 + gy * 64 + x] : 0.f;
    }
    for (int i = tid; i < 90; i += 256) {
        int ry = i % 10, ci = i / 10;
        lds[ci][ry][0] = 0.f; lds[ci][ry][65] = 0.f;
    }
    __syncthreads();
    int co   = tid >> 6;
    int ysub = (tid >> 3) & 7;
    int x0   = (tid & 7) * 8;
    int ocg  = g * 4 + co;
    float acc[8];
    float bias = bs[ocg];
#pragma unroll
    for (int j = 0; j < 8; ++j) acc[j] = bias;
    const float* wb = w + ocg * 81;
    for (int ci = 0; ci < 9; ++ci) {
        float wr[9];
#pragma unroll
        for (int k = 0; k < 9; ++k) wr[k] = wb[ci * 9 + k];
#pragma unroll
        for (int dy = 0; dy < 3; ++dy) {
            const float* lr = &lds[ci][ysub + dy][x0];
            float a = lr[0], bb = lr[1];
#pragma unroll
            for (int j = 0; j < 8; ++j) {
                float cc = lr[2 + j];
                acc[j] += wr[dy * 3] * a + wr[dy * 3 + 1] * bb + wr[dy * 3 + 2] * cc;
                a = bb; bb = cc;
            }
        }
    }
    float* ob = out + ((size_t)b * 64 + ocg) * 4096 + (y0 + ysub) * 64 + x0;
#pragma unroll
    for (int j = 0; j < 8; ++j) ob[j] = acc[j];
}

// L2 norms of q/k rows
__device__ __forceinline__ void qknorm_body(char* smem_raw, int row,
    const float* __restrict__ qkv_dw, float* __restrict__ nrm)
{
    float* red = (float*)smem_raw;
    int which = row >> 10;
    int r = row & 1023;
    int b = r >> 6, hd = r & 63;
    const float* p = qkv_dw + ((size_t)b * 192 + which * 64 + hd) * 4096;
    float s = 0.f;
    for (int i = threadIdx.x; i < 4096; i += 256) { float v = p[i]; s += v * v; }
    red[threadIdx.x] = s;
    __syncthreads();
    for (int st = 128; st > 0; st >>= 1) {
        if (threadIdx.x < st) red[threadIdx.x] += red[threadIdx.x + st];
        __syncthreads();
    }
    if (threadIdx.x == 0) nrm[row] = sqrtf(red[0]);
}

// channel attention partials (arena-based LDS: 16640 B)
__device__ __forceinline__ void chan_attn_part_body(char* smem_raw, int blk,
    const float* __restrict__ qkv_dw, float* __restrict__ part)
{
    auto Qs  = (float(*)[130])smem_raw;
    auto Ks2 = (float(*)[130])(smem_raw + 16 * 130 * 4);
    int nc = blk & 7;
    int bh = blk >> 3;
    int b = bh >> 2, h = bh & 3;
    int c = threadIdx.x >> 4, d = threadIdx.x & 15;
    const float* qbase = qkv_dw + ((size_t)b * 192 + h * 16) * 4096 + nc * 512;
    const float* kbase = qkv_dw + ((size_t)b * 192 + 64 + h * 16) * 4096 + nc * 512;
    float s = 0.f;
    for (int n0 = 0; n0 < 512; n0 += 128) {
        __syncthreads();
        for (int r = 0; r < 8; ++r) {
            int i = (r << 8) + threadIdx.x;
            int row = i >> 7, col = i & 127;
            Qs[row][col]  = qbase[(size_t)row * 4096 + n0 + col];
            Ks2[row][col] = kbase[(size_t)row * 4096 + n0 + col];
        }
        __syncthreads();
#pragma unroll 8
        for (int n = 0; n < 128; ++n) s += Qs[c][n] * Ks2[d][n];
    }
    part[(size_t)blk * 256 + threadIdx.x] = s;
}

// channel pooling (wave-per-row shuffle reduction)
__device__ __forceinline__ void chpool2_body(int bid, const float* __restrict__ t1,
    const float* __restrict__ t2, float* __restrict__ chpool)
{
    int rg = bid & 15;
    int b  = bid >> 4;
    int wave = threadIdx.x >> 6, lane = threadIdx.x & 63;
    int c = rg * 4 + wave;
    const float* p1 = t1 + ((size_t)b * 64 + c) * 1024;
    const float* p2 = t2 + ((size_t)b * 64 + c) * 1024;
    float m1 = 0.f, x1 = -3e38f, m2 = 0.f, x2 = -3e38f;
#pragma unroll
    for (int i = 0; i < 16; ++i) {
        int p = lane + i * 64;
        float a = p1[p], bb = p2[p];
        m1 += a; x1 = fmaxf(x1, a);
        m2 += bb; x2 = fmaxf(x2, bb);
    }
    for (int off = 32; off > 0; off >>= 1) {
        m1 += __shfl_xor(m1, off);
        x1 = fmaxf(x1, __shfl_xor(x1, off));
        m2 += __shfl_xor(m2, off);
        x2 = fmaxf(x2, __shfl_xor(x2, off));
    }
    if (lane == 0) {
        chpool[b * 256 + c]       = m1 * (1.f / 1024.f);
        chpool[b * 256 + 64 + c]  = x1;
        chpool[b * 256 + 128 + c] = m2 * (1.f / 1024.f);
        chpool[b * 256 + 192 + c] = x2;
    }
}

// spatial pooling over channels
__device__ __forceinline__ void sppool_body(int bid, const float* __restrict__ t1,
    const float* __restrict__ t2, float* __restrict__ sppool)
{
    int b = bid >> 2;
    int p = (bid & 3) * 256 + threadIdx.x;
    float m1 = 0.f, x1 = -3e38f, m2 = 0.f, x2 = -3e38f;
    const float* p1 = t1 + (size_t)b * 65536 + p;
    const float* p2 = t2 + (size_t)b * 65536 + p;
    for (int c = 0; c < 64; ++c) {
        float a = p1[c * 1024], bb = p2[c * 1024];
        m1 += a; x1 = fmaxf(x1, a);
        m2 += bb; x2 = fmaxf(x2, bb);
    }
    sppool[b * 4096 + p]        = m1 * (1.f / 64.f);
    sppool[b * 4096 + 1024 + p] = x1;
    sppool[b * 4096 + 2048 + p] = m2 * (1.f / 64.f);
    sppool[b * 4096 + 3072 + p] = x2;
}

// channel gates (first 64 threads active)
__device__ __forceinline__ void chgate_body(int b, const float* __restrict__ chpool,
    const float* __restrict__ w1, const float* __restrict__ b1,
    const float* __restrict__ w2, const float* __restrict__ b2, float* __restrict__ chw)
{
    int c = threadIdx.x;
    if (c >= 64) return;
    float a1 = b1[0], a2 = b2[0];
    for (int ic = 0; ic < 4; ++ic) {
        const float* cp = chpool + b * 256 + ic * 64;
        for (int d = -1; d <= 1; ++d) {
            int cc = c + d;
            if (cc >= 0 && cc < 64) {
                a1 += w1[ic * 3 + d + 1] * cp[cc];
                a2 += w2[ic * 3 + d + 1] * cp[cc];
            }
        }
    }
    float mx = fmaxf(a1, a2);
    float e1 = __expf(a1 - mx), e2 = __expf(a2 - mx);
    float inv = 1.f / (e1 + e2);
    chw[b * 64 + c]        = e1 * inv;
    chw[1024 + b * 64 + c] = e2 * inv;
}

// spatial gates
__device__ __forceinline__ void spgate_body(int bid, const float* __restrict__ sppool,
    const float* __restrict__ w1, const float* __restrict__ b1,
    const float* __restrict__ w2, const float* __restrict__ b2, float* __restrict__ spw)
{
    int idx = bid * 256 + threadIdx.x;
    int p = idx & 1023;
    int b = idx >> 10;
    int y = p >> 5, x = p & 31;
    float a1 = b1[0], a2 = b2[0];
    for (int ic = 0; ic < 4; ++ic) {
        const float* sp = sppool + b * 4096 + ic * 1024;
        for (int dy = -3; dy <= 3; ++dy) {
            int yy = y + dy;
            if (yy < 0 || yy > 31) continue;
            for (int dx = -3; dx <= 3; ++dx) {
                int xx = x + dx;
                if (xx < 0 || xx > 31) continue;
                float v = sp[yy * 32 + xx];
                int wi = ic * 49 + (dy + 3) * 7 + (dx + 3);
                a1 += w1[wi] * v;
                a2 += w2[wi] * v;
            }
        }
    }
    float mx = fmaxf(a1, a2);
    float e1 = __expf(a1 - mx), e2 = __expf(a2 - mx);
    float inv = 1.f / (e1 + e2);
    spw[idx]         = e1 * inv;
    spw[16384 + idx] = e2 * inv;
}

// zero bodies
__device__ __forceinline__ void zero_body(int bid, float* o1t, float* o2t, float* lsg,
                                          unsigned* kmax2)
{
    int idx = bid * 256 + threadIdx.x;
    if (idx < 1048576) { o1t[idx] = 0.f; o2t[idx] = 0.f; }
    if (idx < 131072) lsg[idx] = 0.f;
    if (idx < 128) kmax2[idx] = 0u;
}

// chan_attn merge + softmax body
__device__ __forceinline__ void chan_attn_merge_body(int bh,
    const float* __restrict__ part, const float* __restrict__ nrm,
    const float* __restrict__ temp, float* __restrict__ attn_s)
{
    __shared__ float S[16][17];
    int b = bh >> 2, h = bh & 3;
    int c = threadIdx.x >> 4, d = threadIdx.x & 15;
    float s = 0.f;
#pragma unroll
    for (int i = 0; i < 8; ++i) s += part[(size_t)(bh * 8 + i) * 256 + threadIdx.x];
    float nq = fmaxf(nrm[b * 64 + h * 16 + c], 1e-12f);
    float nk = fmaxf(nrm[1024 + b * 64 + h * 16 + d], 1e-12f);
    s = s / (nq * nk) * temp[h];
    S[c][d] = s;
    __syncthreads();
    if (threadIdx.x < 16) {
        int cc = threadIdx.x;
        float mx = -3e30f;
        for (int dd = 0; dd < 16; ++dd) mx = fmaxf(mx, S[cc][dd]);
        float sm = 0.f;
        float e[16];
        for (int dd = 0; dd < 16; ++dd) { e[dd] = __expf(S[cc][dd] - mx); sm += e[dd]; }
        float inv = 1.f / sm;
        float* dst = attn_s + (size_t)bh * 256 + cc * 16;
        for (int dd = 0; dd < 16; ++dd) dst[dd] = e[dd] * inv;
    }
}

// ===========================================================================
// Fused dispatcher kernels
// ===========================================================================

__global__ __launch_bounds__(256) void s1_kernel(const float* us_in, const float* uw, const float* ub,
    float* uo, const float* iin, const float* iw, const float* ib, float* io)
{
    __shared__ __align__(16) char smem[3168];
    if (blockIdx.x < 512) conv1d3_body<1, 16>(smem, blockIdx.x, us_in, uw, ub, uo);
    else                  conv2d3_body<3, 16, 2>(smem, blockIdx.x - 512, iin, iw, ib, io);
}

__global__ __launch_bounds__(256) void s2_kernel(const float* ui, const float* uw, const float* ub,
    float* uo, const float* ii, const float* iw, const float* ib, float* io)
{
    __shared__ __align__(16) char smem[16896];
    if (blockIdx.x < 512) conv1d3_body<16, 32>(smem, blockIdx.x, ui, uw, ub, uo);
    else                  conv2d3_body<16, 32, 2>(smem, blockIdx.x - 512, ii, iw, ib, io);
}

__global__ __launch_bounds__(256) void s3_kernel(const float* ui, const float* uw, const float* ub,
    float* uo, const float* ii, const float* iw, const float* ib, float* io)
{
    __shared__ __align__(16) char smem[33792];
    if (blockIdx.x < 512) conv1d3_body<32, 64>(smem, blockIdx.x, ui, uw, ub, uo);
    else                  conv2d3_body<32, 64, 2>(smem, blockIdx.x - 512, ii, iw, ib, io);
}

__global__ __launch_bounds__(256) void s4_kernel(const float* us3, float* xf,
    const float* y, const float* qw, const float* qb, float* qkv)
{
    __shared__ __align__(16) char smem[32768];
    if (blockIdx.x < 1024) fft_fwd_body(smem, blockIdx.x, us3, xf);
    else                   qkv1x1_body(blockIdx.x - 1024, y, qw, qb, qkv);
}

// s5: LDS-tiled depthwise conv (3072 blocks) || spectral energy (129)
__global__ __launch_bounds__(256) void s5_kernel(const float* qkv, const float* dww,
    const float* dwb, float* qkv_dw, const float* xf, float* energy)
{
    __shared__ __align__(16) char smem[66 * 66 * 4];
    if (blockIdx.x < 3072) dwconv2_body(smem, blockIdx.x, qkv, dww, dwb, qkv_dw);
    else                   energy_body(blockIdx.x - 3072, xf, energy);
}

// s6: fc || median || chan_attn partials (arena 16640 B)
__global__ __launch_bounds__(256) void s6_kernel(const float* qkv_dw, const float* fw,
    const float* fb, float* fcv, const float* energy, float* med, float* part)
{
    __shared__ __align__(16) char smem[16640];
    if (blockIdx.x < 4096)      fc_body(blockIdx.x, qkv_dw, fw, fb, fcv);
    else if (blockIdx.x < 4112) median_body(smem, blockIdx.x - 4096, energy, med);
    else                        chan_attn_part_body(smem, blockIdx.x - 4112, qkv_dw, part);
}

// s7: depconv || qknorm || filter+irfft+pool (arena 32 KB)
__global__ __launch_bounds__(256) void s7_kernel(const float* fcv, const float* dw,
    const float* db, float* out_conv, const float* qkv_dw, float* nrm,
    const float* xf, const float* energy, const float* med, const float* aw,
    const float* awh, const float* thr, float* us_redT)
{
    __shared__ __align__(16) char smem[32768];
    if (blockIdx.x < 2048)      depconv2_body(smem, blockIdx.x, fcv, dw, db, out_conv);
    else if (blockIdx.x < 4096) qknorm_body(smem, blockIdx.x - 2048, qkv_dw, nrm);
    else                        filter_ifft_body(smem, blockIdx.x - 4096, xf, energy, med, aw, awh, thr, us_redT);
}

// zm: zero accumulators (4096 blocks) || chan_attn merge+softmax (64)
__global__ __launch_bounds__(256) void zm_kernel(float* o1t, float* o2t, float* lsg,
    unsigned* kmax2, const float* part, const float* nrm, const float* temp, float* attn_s)
{
    if (blockIdx.x < 4096) zero_body(blockIdx.x, o1t, o2t, lsg, kmax2);
    else                   chan_attn_merge_body(blockIdx.x - 4096, part, nrm, temp, attn_s);
}

__global__ __launch_bounds__(256) void s16_kernel(const float* t1, const float* t2,
    float* chpool, float* sppool)
{
    if (blockIdx.x < 256) chpool2_body(blockIdx.x, t1, t2, chpool);
    else                  sppool_body(blockIdx.x - 256, t1, t2, sppool);
}

__global__ __launch_bounds__(256) void s17_kernel(const float* sppool, const float* sw1,
    const float* sb1, const float* sw2, const float* sb2, float* spw,
    const float* chpool, const float* cw1, const float* cb1, const float* cw2,
    const float* cb2, float* chw)
{
    if (blockIdx.x < 64) spgate_body(blockIdx.x, sppool, sw1, sb1, sw2, sb2, spw);
    else                 chgate_body(blockIdx.x - 64, chpool, cw1, cb1, cw2, cb2, chw);
}

// ===========================================================================
// Standalone kernels
// ===========================================================================

// attn@v + 1x1 proj + out_conv add -> img_feat (full; coalesced stores)
__global__ __launch_bounds__(256, 2) void attnproj_kernel(const float* __restrict__ attn_s,
    const float* __restrict__ qkv_dw, const float* __restrict__ outconv,
    const float* __restrict__ pw, const float* __restrict__ pb, float* __restrict__ img_feat)
{
    int blk = blockIdx.x;
    int oc = blk & 1;
    int pc = (blk >> 1) & 15;
    int b  = blk >> 5;
    int n = pc * 256 + threadIdx.x;
    const float* vb = qkv_dw + ((size_t)b * 192 + 128) * 4096 + n;
    v2f v[32];
#pragma unroll
    for (int i = 0; i < 32; ++i) {
        v2f r; r.x = vb[(2 * i) * 4096]; r.y = vb[(2 * i + 1) * 4096];
        v[i] = r;
    }
    const float* ab = attn_s + (size_t)b * 1024;
    for (int h = 0; h < 4; ++h) {
        v2f tmp[8];
#pragma unroll
        for (int c2 = 0; c2 < 8; ++c2) {
            v2f s2a = {0.f, 0.f}, s2b = {0.f, 0.f};
            const v2f* r0 = (const v2f*)(ab + (h * 16 + 2 * c2) * 16);
            const v2f* r1 = (const v2f*)(ab + (h * 16 + 2 * c2 + 1) * 16);
#pragma unroll
            for (int d2 = 0; d2 < 8; ++d2) {
                s2a = r0[d2] * v[h * 8 + d2] + s2a;
                s2b = r1[d2] * v[h * 8 + d2] + s2b;
            }
            v2f t; t.x = s2a.x + s2a.y; t.y = s2b.x + s2b.y;
            tmp[c2] = t;
        }
#pragma unroll
        for (int c2 = 0; c2 < 8; ++c2) v[h * 8 + c2] = tmp[c2];
    }
    float* ofb = img_feat + (size_t)b * 262144 + (size_t)oc * 32 * 4096 + n;
    const float* ocb = outconv + (size_t)b * 262144 + (size_t)oc * 32 * 4096 + n;
    for (int o = 0; o < 32; ++o) {
        const v2f* wr = (const v2f*)(pw + (oc * 32 + o) * 64);
        v2f s2 = {0.f, 0.f};
#pragma unroll
        for (int c2 = 0; c2 < 32; ++c2) s2 = wr[c2] * v[c2] + s2;
        ofb[o * 4096] = pb[oc * 32 + o] + ocb[o * 4096] + s2.x + s2.y;
    }
}

// 4:1 pool of img_feat -> img_redT (coalesced float4 reads, coalesced stores)
__global__ __launch_bounds__(256) void poolred_img_kernel(const float* __restrict__ img_feat,
    float* __restrict__ img_redT)
{
    int idx = blockIdx.x * 256 + threadIdx.x;
    int s4 = idx & 1023;
    int bc = idx >> 10;
    const float* in = img_feat + (size_t)bc * 4096 + s4 * 4;
    float4 v4 = *(const float4*)in;
    img_redT[(size_t)bc * 1024 + s4] = 0.25f * (v4.x + v4.y + v4.z + v4.w);
}

// shared qkv projection with FUSED kmax (wave-reduced atomicMax of k-norm^2)
__global__ __launch_bounds__(256, 2) void caqkv2_kernel(const float* __restrict__ us_redT,
    const float* __restrict__ img_redT, const float* __restrict__ qw, const float* __restrict__ qb,
    float* __restrict__ q1, float* __restrict__ k1, float* __restrict__ v1,
    float* __restrict__ q2, float* __restrict__ k2, float* __restrict__ v2,
    unsigned* __restrict__ kmax2)
{
    int blk = blockIdx.x;
    int h  = blk & 3;
    int pc = (blk >> 2) & 3;
    int b  = (blk >> 4) & 15;
    int m  = blk >> 8;
    int l = pc * 256 + threadIdx.x;
    const float* in = (m ? img_redT : us_redT) + (size_t)b * 65536 + l;
    v2f reg[32];
#pragma unroll
    for (int i = 0; i < 32; ++i) {
        v2f r; r.x = in[(2 * i) * 1024]; r.y = in[(2 * i + 1) * 1024];
        reg[i] = r;
    }
    size_t rowoff = ((size_t)(b * 4 + h) * 1024 + l) * 16;
    float* dst[3] = { (m ? q2 : q1) + rowoff, (m ? k2 : k1) + rowoff, (m ? v2 : v1) + rowoff };
    float knorm2 = 0.f;
#pragma unroll
    for (int which = 0; which < 3; ++which) {
        float* dp = dst[which];
        for (int d = 0; d < 16; ++d) {
            int o = h * 48 + which * 16 + d;
            const v2f* wr = (const v2f*)(qw + o * 64);
            v2f s2 = {0.f, 0.f};
#pragma unroll
            for (int i = 0; i < 32; ++i) s2 = wr[i] * reg[i] + s2;
            float val = qb[o] + s2.x + s2.y;
            dp[d] = val;
            if (which == 1) knorm2 += val * val;
        }
    }
    for (int off = 32; off > 0; off >>= 1)
        knorm2 = fmaxf(knorm2, __shfl_xor(knorm2, off));
    if ((threadIdx.x & 63) == 0) {
        int unit = b * 8 + (1 - m) * 4 + h;
        atomicMax(&kmax2[unit], __float_as_uint(knorm2));
    }
}

// cross-modal attention v9 (kmax^2 input): LDS-staged, NQ=4, bound-max,
// packed fp32, KT=8, atomic accumulation into o1t/o2t/ls.
__global__ __launch_bounds__(256, 2) void cross_attn9_kernel(
    const float* __restrict__ q1, const float* __restrict__ k1, const float* __restrict__ v1,
    const float* __restrict__ q2, const float* __restrict__ k2, const float* __restrict__ v2,
    const unsigned* __restrict__ kmax2, float* __restrict__ ls_glob,
    float* __restrict__ o1t, float* __restrict__ o2t)
{
    int blk  = blockIdx.x;         // 1024 = 128 units * 8 kt
    int kt   = blk & 7;
    int unit = blk >> 3;
    int h = unit & 3;
    int m = (unit >> 2) & 1;
    int b = unit >> 3;
    const float* Q = m ? q2 : q1;
    const float* K = m ? k1 : k2;
    const float* V = m ? v1 : v2;
    const float* Qb = Q + (size_t)(b * 4 + h) * 16384;
    const float* Kb = K + (size_t)(b * 4 + h) * 16384 + kt * 128 * 16;
    const float* Vb = V + (size_t)(b * 4 + h) * 16384 + kt * 128 * 16;
    int tid = threadIdx.x;
    const float SC = 0.25f * 1.44269504088896340736f;
    float km = sqrtf(__uint_as_float(kmax2[unit]));
    v2f qr[4][8], acc[4][8];
    float M[4], ls[4];
#pragma unroll
    for (int j = 0; j < 4; ++j) {
        const v2f* qp = (const v2f*)(Qb + (size_t)(tid + 256 * j) * 16);
        v2f qs2 = {0.f, 0.f};
#pragma unroll
        for (int i = 0; i < 8; ++i) {
            v2f q = qp[i];
            qs2 = q * q + qs2;
            qr[j][i] = q * SC;
        }
        M[j] = sqrtf(qs2.x + qs2.y) * km * SC;
        ls[j] = 0.f;
#pragma unroll
        for (int i = 0; i < 8; ++i) acc[j][i] = (v2f){0.f, 0.f};
    }
    __shared__ float Ks[64 * 16];
    __shared__ float Vs[64 * 16];
    for (int t0 = 0; t0 < 128; t0 += 64) {
        __syncthreads();
        ((float4*)Ks)[tid] = ((const float4*)(Kb + t0 * 16))[tid];
        ((float4*)Vs)[tid] = ((const float4*)(Vb + t0 * 16))[tid];
        __syncthreads();
#pragma unroll 2
        for (int t = 0; t < 64; ++t) {
            const v2f* k2p = (const v2f*)&Ks[t * 16];
            v2f kk[8];
#pragma unroll
            for (int i = 0; i < 8; ++i) kk[i] = k2p[i];
            float p[4];
#pragma unroll
            for (int j = 0; j < 4; ++j) {
                v2f s2 = {0.f, 0.f};
#pragma unroll
                for (int i = 0; i < 8; ++i) s2 = qr[j][i] * kk[i] + s2;
                p[j] = exp2f(s2.x + s2.y - M[j]);
                ls[j] += p[j];
            }
            const v2f* v2p = (const v2f*)&Vs[t * 16];
            v2f vv[8];
#pragma unroll
            for (int i = 0; i < 8; ++i) vv[i] = v2p[i];
#pragma unroll
            for (int j = 0; j < 4; ++j) {
                v2f pj = {p[j], p[j]};
#pragma unroll
                for (int i = 0; i < 8; ++i) acc[j][i] = pj * vv[i] + acc[j][i];
            }
        }
    }
    float* obase = (m ? o2t : o1t) + (size_t)b * 65536 + (size_t)(h * 16) * 1024;
#pragma unroll
    for (int j = 0; j < 4; ++j) {
        int q = tid + 256 * j;
        atomicAdd(&ls_glob[(size_t)unit * 1024 + q], ls[j]);
        float* onum = obase + q;
#pragma unroll
        for (int i = 0; i < 8; ++i) {
            atomicAdd(&onum[(2 * i) * 1024], acc[j][i].x);
            atomicAdd(&onum[(2 * i + 1) * 1024], acc[j][i].y);
        }
    }
}

// output projection with fused 1/ls normalization
__global__ __launch_bounds__(256, 2) void caout3_kernel(const float* __restrict__ o1t,
    const float* __restrict__ o2t, const float* __restrict__ ls_glob,
    const float* __restrict__ ow, const float* __restrict__ ob_,
    float* __restrict__ t1, float* __restrict__ t2)
{
    int blk = blockIdx.x;
    int oc = blk & 1;
    int pc = (blk >> 1) & 3;
    int b  = (blk >> 3) & 15;
    int m  = blk >> 7;
    int l = pc * 256 + threadIdx.x;
    float inv[4];
#pragma unroll
    for (int h = 0; h < 4; ++h)
        inv[h] = 1.f / ls_glob[(size_t)(b * 8 + m * 4 + h) * 1024 + l];
    const float* in = (m ? o2t : o1t) + (size_t)b * 65536 + l;
    v2f reg[32];
#pragma unroll
    for (int i = 0; i < 32; ++i) {
        float iv = inv[i >> 3];
        v2f r; r.x = in[(2 * i) * 1024] * iv; r.y = in[(2 * i + 1) * 1024] * iv;
        reg[i] = r;
    }
    float* t = (m ? t2 : t1) + (size_t)b * 65536 + (size_t)oc * 32 * 1024 + l;
    for (int o = 0; o < 32; ++o) {
        const v2f* wr = (const v2f*)(ow + (oc * 32 + o) * 64);
        v2f s2 = {0.f, 0.f};
#pragma unroll
        for (int i = 0; i < 32; ++i) s2 = wr[i] * reg[i] + s2;
        t[o * 1024] = ob_[oc * 32 + o] + s2.x + s2.y;
    }
}

__global__ __launch_bounds__(256) void final2_kernel(const float* __restrict__ t1,
    const float* __restrict__ t2, const float* __restrict__ chw, const float* __restrict__ spw,
    const float* __restrict__ clsw, const float* __restrict__ clsb, float* __restrict__ out)
{
    int b = blockIdx.x;
    int wave = threadIdx.x >> 6, lane = threadIdx.x & 63;
    __shared__ float feat[64];
    __shared__ float lg[9];
    const float* s1 = spw + b * 1024;
    const float* s2 = spw + 16384 + b * 1024;
    for (int round = 0; round < 16; ++round) {
        int c = round * 4 + wave;
        float g1 = chw[b * 64 + c] + 1.f;
        float g2 = chw[1024 + b * 64 + c] + 1.f;
        const float* p1 = t1 + ((size_t)b * 64 + c) * 1024;
        const float* p2 = t2 + ((size_t)b * 64 + c) * 1024;
        float acc = 0.f;
#pragma unroll
        for (int i = 0; i < 16; ++i) {
            int p = lane + i * 64;
            acc += (g1 + s1[p]) * p1[p] + (g2 + s2[p]) * p2[p];
        }
        for (int off = 32; off > 0; off >>= 1) acc += __shfl_xor(acc, off);
        if (lane == 0) feat[c] = acc * (1.f / 1024.f);
    }
    __syncthreads();
    if (threadIdx.x < 9) {
        int c = threadIdx.x;
        float s = clsb[c];
        for (int i = 0; i < 64; ++i) s += clsw[c * 64 + i] * feat[i];
        lg[c] = s;
    }
    __syncthreads();
    if (threadIdx.x == 0) {
        float mx = -3e38f;
        for (int o = 0; o < 9; ++o) mx = fmaxf(mx, lg[o]);
        float sm = 0.f;
        float e[9];
        for (int o = 0; o < 9; ++o) { e[o] = __expf(lg[o] - mx); sm += e[o]; }
        float inv = 1.f / sm;
        for (int o = 0; o < 9; ++o) out[b * 9 + o] = e[o] * inv;
    }
}

// ---------------------------------------------------------------------------
extern "C" void kernel_launch(void* const* d_in, const int* in_sizes, int n_in,
                              void* d_out, int out_size, void* d_ws, size_t ws_size,
                              hipStream_t stream)
{
    (void)in_sizes; (void)n_in; (void)out_size; (void)ws_size;
    const float* us_input = (const float*)d_in[0];
    const float* img_input = (const float*)d_in[1];
    const float* us_w1 = (const float*)d_in[2];  const float* us_b1 = (const float*)d_in[3];
    const float* us_w2 = (const float*)d_in[4];  const float* us_b2 = (const float*)d_in[5];
    const float* us_w3 = (const float*)d_in[6];  const float* us_b3 = (const float*)d_in[7];
    const float* aff_w = (const float*)d_in[8];  const float* aff_wh = (const float*)d_in[9];
    const float* aff_thr = (const float*)d_in[10];
    const float* img_w1 = (const float*)d_in[11]; const float* img_b1 = (const float*)d_in[12];
    const float* img_w2 = (const float*)d_in[13]; const float* img_b2 = (const float*)d_in[14];
    const float* img_w3 = (const float*)d_in[15]; const float* img_b3 = (const float*)d_in[16];
    const float* db_qkv_w = (const float*)d_in[17]; const float* db_qkv_b = (const float*)d_in[18];
    const float* db_dw_w = (const float*)d_in[19];  const float* db_dw_b = (const float*)d_in[20];
    const float* db_proj_w = (const float*)d_in[21]; const float* db_proj_b = (const float*)d_in[22];
    const float* db_fc_w = (const float*)d_in[23];  const float* db_fc_b = (const float*)d_in[24];
    const float* db_dep_w = (const float*)d_in[25]; const float* db_dep_b = (const float*)d_in[26];
    const float* db_temp = (const float*)d_in[27];
    const float* ca_qkv_w = (const float*)d_in[28]; const float* ca_qkv_b = (const float*)d_in[29];
    const float* ca_out_w = (const float*)d_in[30]; const float* ca_out_b = (const float*)d_in[31];
    const float* tf_ch1_w = (const float*)d_in[32]; const float* tf_ch1_b = (const float*)d_in[33];
    const float* tf_ch2_w = (const float*)d_in[34]; const float* tf_ch2_b = (const float*)d_in[35];
    const float* tf_sp1_w = (const float*)d_in[36]; const float* tf_sp1_b = (const float*)d_in[37];
    const float* tf_sp2_w = (const float*)d_in[38]; const float* tf_sp2_b = (const float*)d_in[39];
    const float* cls_w = (const float*)d_in[40];   const float* cls_b = (const float*)d_in[41];

    float* ws = (float*)d_ws;
    float* us1     = ws + O_SMALL;
    float* us2     = ws + O_SMALL + 1048576;
    float* us3     = ws + O_US3;
    float* xf      = ws + O_XF;
    float* energy  = ws + O_ENERGY;
    float* med     = ws + O_MED;
    float* nrm     = ws + O_NRM;
    float* attn_s  = ws + O_ATTNS;
    float* chpool  = ws + O_CHPOOL;
    float* chw     = ws + O_CHW;
    float* sppool  = ws + O_SPPOOL;
    float* spw     = ws + O_SPW;
    float* qkv     = ws + O_QKV;
    float* qkv_dw  = ws + O_QKVDW;
    float* out_conv= ws + O_OUTCONV;
    float* img1 = ws + O_USFILT;
    float* img2 = ws + O_USFILT + 1048576;
    float* y = ws + O_QKVDW;               // dead before dwconv writes qkv_dw
    float* fcv = qkv;                      // qkv dead after dwconv
    float* img_feat = xf;                  // xf dead after s7's filt branch
    float* ca_part = ws + O_SMALL;         // us1/us2 dead after s3
    float* ca_ls    = ws + O_US3;
    unsigned* ca_kmax2 = (unsigned*)(ws + O_US3 + 131072);
    float* us_redT  = ws + O_US3 + 262144;
    float* img_redT = ws + O_US3 + 1310720;
    float* q1 = ws + O_QKV + CA_Q1 * 1048576;
    float* k1 = ws + O_QKV + CA_K1 * 1048576;
    float* v1 = ws + O_QKV + CA_V1 * 1048576;
    float* q2 = ws + O_QKV + CA_Q2 * 1048576;
    float* k2 = ws + O_QKV + CA_K2 * 1048576;
    float* v2 = ws + O_QKV + CA_V2 * 1048576;
    float* o1t = ws + O_QKV + CA_O1 * 1048576;
    float* o2t = ws + O_QKV + CA_O2 * 1048576;
    float* t1 = ws + O_QKV + CA_T1 * 1048576;
    float* t2 = ws + O_QKV + CA_T2 * 1048576;

    // S1..S3: fused conv stages (US branch || IMG branch)
    s1_kernel<<<1024, 256, 0, stream>>>(us_input, us_w1, us_b1, us1,
                                        img_input, img_w1, img_b1, img1);
    s2_kernel<<<1024, 256, 0, stream>>>(us1, us_w2, us_b2, us2,
                                        img1, img_w2, img_b2, img2);
    s3_kernel<<<1024, 256, 0, stream>>>(us2, us_w3, us_b3, us3,
                                        img2, img_w3, img_b3, y);
    // S4: rfft || qkv 1x1
    s4_kernel<<<2048, 256, 0, stream>>>(us3, xf, y, db_qkv_w, db_qkv_b, qkv);
    // S5: LDS-tiled depthwise conv || spectral energy
    s5_kernel<<<3201, 256, 0, stream>>>(qkv, db_dw_w, db_dw_b, qkv_dw, xf, energy);
    // S6: fc || median || chan_attn partials
    s6_kernel<<<4624, 256, 0, stream>>>(qkv_dw, db_fc_w, db_fc_b, fcv, energy, med, ca_part);
    // S7: grouped conv || qknorm || filter+irfft+pool (-> us_redT directly)
    s7_kernel<<<5120, 256, 0, stream>>>(fcv, db_dep_w, db_dep_b, out_conv,
                                        qkv_dw, nrm, xf, energy, med,
                                        aff_w, aff_wh, aff_thr, us_redT);
    // zero accumulators || chan_attn merge+softmax
    zm_kernel<<<4160, 256, 0, stream>>>(o1t, o2t, ca_ls, ca_kmax2,
                                        ca_part, nrm, db_temp, attn_s);
    // attnproj: full img_feat (coalesced stores), then coalesced 4:1 pool
    attnproj_kernel<<<512, 256, 0, stream>>>(attn_s, qkv_dw, out_conv, db_proj_w, db_proj_b, img_feat);
    poolred_img_kernel<<<4096, 256, 0, stream>>>(img_feat, img_redT);
    // caqkv with fused kmax
    caqkv2_kernel<<<512, 256, 0, stream>>>(us_redT, img_redT, ca_qkv_w, ca_qkv_b,
                                           q1, k1, v1, q2, k2, v2, ca_kmax2);
    cross_attn9_kernel<<<1024, 256, 0, stream>>>(q1, k1, v1, q2, k2, v2, ca_kmax2,
                                                 ca_ls, o1t, o2t);
    caout3_kernel<<<256, 256, 0, stream>>>(o1t, o2t, ca_ls, ca_out_w, ca_out_b, t1, t2);
    // S16/S17: fused pooling and gates
    s16_kernel<<<320, 256, 0, stream>>>(t1, t2, chpool, sppool);
    s17_kernel<<<80, 256, 0, stream>>>(sppool, tf_sp1_w, tf_sp1_b, tf_sp2_w, tf_sp2_b, spw,
                                       chpool, tf_ch1_w, tf_ch1_b, tf_ch2_w, tf_ch2_b, chw);
    final2_kernel<<<16, 256, 0, stream>>>(t1, t2, chw, spw, cls_w, cls_b, (float*)d_out);
}